// Round 11
// baseline (287.205 us; speedup 1.0000x reference)
//
#include <hip/hip_runtime.h>
#include <hip/hip_bf16.h>
#include <cstdint>

#define B_ 4
#define C_ 512
#define N_ 4096

typedef unsigned short u16;
typedef unsigned char u8;
typedef __bf16 bf16x8 __attribute__((ext_vector_type(8)));
typedef float f32x4 __attribute__((ext_vector_type(4)));

union U16B { uint4 u; bf16x8 v; };

__device__ __forceinline__ bf16x8 ld16g(const u16* p) {
  U16B t; t.u = *(const uint4*)p; return t.v;
}

__device__ __forceinline__ u16 f2bf(float f) {
  uint32_t u = __builtin_bit_cast(uint32_t, f);
  u = (u + 0x7FFFu + ((u >> 16) & 1u)) >> 16;
  return (u16)u;
}
__device__ __forceinline__ float bf2f(u16 h) {
  uint32_t u = ((uint32_t)h) << 16;
  return __builtin_bit_cast(float, u);
}

// f32 -> fp8 e4m3fn (OCP), RNE (validated r8-r10). Used for q/k/v projections.
__device__ __forceinline__ u8 f2fp8(float f) {
  uint32_t u = __builtin_bit_cast(uint32_t, f);
  uint32_t s = (u >> 24) & 0x80u;
  uint32_t a = u & 0x7FFFFFFFu;
  if (a >= 0x43700000u) return (u8)(s | 0x7E);
  if (a < 0x3C800000u) {
    float af = __builtin_bit_cast(float, a);
    int m = (int)(af * 512.0f + 0.5f);
    return (u8)(s | (uint32_t)m);
  }
  uint32_t r = (a + 0x7FFFFu + ((a >> 20) & 1u)) >> 20;
  return (u8)(s | (r - (120u << 3)));
}

// f32 -> bf8 e5m2 for positive P: f16 cvt + RNE truncate of high byte (~5 ops)
__device__ __forceinline__ u8 f2bf8pos(float f) {
  _Float16 h = (_Float16)f;
  u16 hb = __builtin_bit_cast(unsigned short, h);
  hb = (u16)(hb + 0x7Fu + ((hb >> 8) & 1u));
  return (u8)(hb >> 8);
}

typedef const __attribute__((address_space(1))) uint32_t* gas_p;
typedef __attribute__((address_space(3))) uint32_t* las_p;
__device__ __forceinline__ void gld16(const void* g, void* l) {
  __builtin_amdgcn_global_load_lds((gas_p)g, (las_p)l, 16, 0, 0);
}

#define SCEXP 0.06376149809794171f  /* 512^-0.5 * log2(e) */

// ---------------- K0: f32 -> bf16 weight convert (512x512 each) -------------
__global__ __launch_bounds__(256) void cvt_w(const float* __restrict__ w, u16* __restrict__ o) {
  int i = blockIdx.x * 256 + threadIdx.x;
  float4 v = ((const float4*)w)[i];
  ushort4 r;
  r.x = f2bf(v.x); r.y = f2bf(v.y); r.z = f2bf(v.z); r.w = f2bf(v.w);
  ((ushort4*)o)[i] = r;
}

// ---------------- K0b: pack [bq; bk] -> 1024 f32 ----------------------------
__global__ __launch_bounds__(1024) void pack_bias(const float* __restrict__ bq,
    const float* __restrict__ bk, float* __restrict__ o) {
  int i = threadIdx.x;
  o[i] = (i < 512) ? bq[i] : bk[i - 512];
}

// ---------------- K1: instance-norm stats per (b,c) over 4096 ---------------
__global__ __launch_bounds__(256) void inorm_stats(const float* __restrict__ x,
    float* __restrict__ mu, float* __restrict__ rstd) {
  int bc = blockIdx.x;
  const float4* p = (const float4*)(x + (size_t)bc * N_);
  float s = 0.f, ss = 0.f;
  for (int i = threadIdx.x; i < N_ / 4; i += 256) {
    float4 v = p[i];
    s  += v.x + v.y + v.z + v.w;
    ss += v.x * v.x + v.y * v.y + v.z * v.z + v.w * v.w;
  }
#pragma unroll
  for (int off = 32; off > 0; off >>= 1) {
    s  += __shfl_down(s, off);
    ss += __shfl_down(ss, off);
  }
  __shared__ float as_[4], ass_[4];
  if ((threadIdx.x & 63) == 0) { as_[threadIdx.x >> 6] = s; ass_[threadIdx.x >> 6] = ss; }
  __syncthreads();
  if (threadIdx.x == 0) {
    float S  = as_[0] + as_[1] + as_[2] + as_[3];
    float SS = ass_[0] + ass_[1] + ass_[2] + ass_[3];
    float m  = S * (1.f / N_);
    float var = SS * (1.f / N_) - m * m;
    mu[bc] = m;
    rstd[bc] = rsqrtf(var + 1e-5f);
  }
}

// ---------------- K2: normalize + transpose -> hT (B,N,C) bf16 --------------
__global__ __launch_bounds__(256) void norm_transpose(const float* __restrict__ x,
    const float* __restrict__ mu, const float* __restrict__ rstd, u16* __restrict__ hT) {
  __shared__ u16 tile[64][66];
  int b = blockIdx.z, c0 = blockIdx.y * 64, n0 = blockIdx.x * 64;
  int tn = threadIdx.x & 63, t4 = threadIdx.x >> 6;
  const float* xb = x + ((size_t)b * C_ + c0) * N_ + n0;
#pragma unroll
  for (int it = 0; it < 16; ++it) {
    int c = t4 + it * 4;
    float m  = mu[b * C_ + c0 + c];
    float rs = rstd[b * C_ + c0 + c];
    tile[c][tn] = f2bf((xb[(size_t)c * N_ + tn] - m) * rs);
  }
  __syncthreads();
  u16* hTb = hT + ((size_t)b * N_ + n0) * C_ + c0;
#pragma unroll
  for (int it = 0; it < 16; ++it) {
    int n = t4 + it * 4;
    hTb[(size_t)n * C_ + tn] = tile[tn][n];
  }
}

// ============== gemm128: BK=64 dbuf projections -> fp8 out (NATURAL layout) =
#define EPI_QK8  2
#define EPI_V8   3

template<int EPI>
__global__ __launch_bounds__(256) void gemm128(
    const u16* __restrict__ A, const u16* __restrict__ B,
    const float* __restrict__ aux, void* __restrict__ Out,
    int klen, int lda, int ldb, int ldo,
    long sAz, long sBz, long sOz)
{
  int z = blockIdx.z;
  const u16* Ab = A + (size_t)z * sAz;
  const u16* Bb = B + (size_t)z * sBz;
  int m0 = blockIdx.x * 128, n0 = blockIdx.y * 128;
  int t = threadIdx.x, w = t >> 6, l = t & 63;
  int wr = w >> 1, wc = w & 1;
  int l16 = l & 15, lg = l >> 4;

  __shared__ char smem[65536];

  int srow = t >> 3;
  int scol = ((t & 7) << 4) ^ ((srow & 7) << 4);
  size_t ldaB = (size_t)lda * 2, ldbB = (size_t)ldb * 2;

  f32x4 acc[4][4] = {};
  int nsteps = klen >> 6;

#define STAGE(step, d) {                                                     \
    size_t kbyte = (size_t)(step) * 128 + scol;                              \
    char* lb = smem + (d) * 32768;                                           \
    _Pragma("unroll")                                                        \
    for (int i = 0; i < 4; ++i) {                                            \
      int row = i * 32 + srow;                                               \
      gld16((const char*)Ab + (size_t)(m0 + row) * ldaB + kbyte,             \
            lb + (size_t)(i * 256 + t) * 16);                                \
      gld16((const char*)Bb + (size_t)(n0 + row) * ldbB + kbyte,             \
            lb + 16384 + (size_t)(i * 256 + t) * 16);                        \
    }                                                                        \
  }

  STAGE(0, 0);
  __syncthreads();
  int cur = 0;
  int sw = (l16 & 7) << 4;
  for (int s = 0; s < nsteps; ++s) {
    if (s + 1 < nsteps) STAGE(s + 1, cur ^ 1);
    const char* Al = smem + cur * 32768;
    const char* Bl = Al + 16384;
#pragma unroll
    for (int kc = 0; kc < 2; ++kc) {
      int cb = (kc * 64 + lg * 16) ^ sw;
      bf16x8 af[4], bf[4];
#pragma unroll
      for (int mf = 0; mf < 4; ++mf)
        af[mf] = *(const bf16x8*)(Al + (wr * 64 + mf * 16 + l16) * 128 + cb);
#pragma unroll
      for (int nf = 0; nf < 4; ++nf)
        bf[nf] = *(const bf16x8*)(Bl + (wc * 64 + nf * 16 + l16) * 128 + cb);
#pragma unroll
      for (int mf = 0; mf < 4; ++mf)
#pragma unroll
        for (int nf = 0; nf < 4; ++nf)
          acc[mf][nf] = __builtin_amdgcn_mfma_f32_16x16x32_bf16(af[mf], bf[nf], acc[mf][nf], 0, 0, 0);
    }
    __syncthreads();
    cur ^= 1;
  }
#undef STAGE

  // fp8 e4m3 epilogue, NATURAL col order, LDS bounce + full-line stores
  u8* ob = (u8*)Out + (size_t)z * sOz;
  char* sb = smem;
  float bc[4];
  if constexpr (EPI == EPI_QK8) {
#pragma unroll
    for (int nf = 0; nf < 4; ++nf) bc[nf] = aux[n0 + wc * 64 + nf * 16 + l16];
  }
#pragma unroll
  for (int mf = 0; mf < 4; ++mf) {
#pragma unroll
    for (int r = 0; r < 4; ++r) {
      int rowl = wr * 64 + mf * 16 + lg * 4 + r;
      float brow = (EPI == EPI_V8) ? aux[m0 + rowl] : 0.f;
#pragma unroll
      for (int nf = 0; nf < 4; ++nf) {
        int cl = wc * 64 + nf * 16 + l16;
        float v = acc[mf][nf][r] + (EPI == EPI_QK8 ? bc[nf] : brow);
        sb[rowl * 128 + cl] = (char)f2fp8(v);
      }
    }
  }
  __syncthreads();
#pragma unroll
  for (int it = 0; it < 4; ++it) {
    int idx = it * 256 + t;
    int row = idx >> 3, seg = idx & 7;
    *(uint4*)(ob + (size_t)(m0 + row) * ldo + n0 + seg * 16) =
        *(const uint4*)(sb + row * 128 + seg * 16);
  }
}

// ============== exp_wave: single-wave 64x64 fp8 QK tile, NO BARRIERS ========
// One 64-lane wave per block; BK=32; 3 LDS buffers, depth-2 vmcnt pipeline.
// Natural-layout inputs; ds_read_b64 operands; P out = bf8 e5m2 (natural).
__global__ __launch_bounds__(64, 2) void exp_wave(
    const u8* __restrict__ qk8, float* __restrict__ dsumAll, u8* __restrict__ Pall)
{
  // XCD chunk + 8x8 supertile (512KB q+k panel per supertile -> L2)
  int fid = blockIdx.x;                  // 16384 blocks
  int rid = (fid & 7) * 2048 + (fid >> 3);
  int z = rid >> 12;
  int r12 = rid & 4095;
  int st = r12 >> 6, w6 = r12 & 63;
  int m0 = ((st >> 3) * 8 + (w6 >> 3)) * 64;
  int n0 = ((st & 7) * 8 + (w6 & 7)) * 64;

  const u8* Ab = qk8 + (size_t)z * ((size_t)N_ * 1024);   // q rows (stride 1024)
  const u8* Bb = Ab + 512;                                // k rows
  float* dsum = dsumAll + (size_t)z * N_;
  u8* Pp = Pall + (size_t)z * (size_t)N_ * N_;

  int l = threadIdx.x, l16 = l & 15, lg = l >> 4;

  __shared__ char smem[12288];          // 3 x (A 2KB + B 2KB)

  f32x4 acc[4][4] = {};
  // read offset: source octet lg of 32B row; granule (lg>>1) XOR'd by (row>>2)&1
  int ga = ((((lg >> 1) ^ ((l16 >> 2) & 1)) << 4) | ((lg & 1) << 3));

  // stage one BK=32 slot (A 2KB + B 2KB): 2 granules/lane/matrix = 4 gld16
#define STGE(s, lb) {                                                        \
    size_t kb = (size_t)(s) * 32;                                            \
    _Pragma("unroll")                                                        \
    for (int i = 0; i < 2; ++i) {                                            \
      int slot = i * 64 + l;                                                 \
      int row = slot >> 1;                                                   \
      int gs = ((slot & 1) ^ ((row >> 2) & 1)) << 4;                         \
      gld16((const char*)Ab + (size_t)(m0 + row) * 1024 + kb + gs,           \
            (lb) + slot * 16);                                               \
      gld16((const char*)Bb + (size_t)(n0 + row) * 1024 + kb + gs,           \
            (lb) + 2048 + slot * 16);                                        \
    }                                                                        \
  }

#define COMPE(lb) {                                                          \
    long long a8[4], b8[4];                                                  \
    _Pragma("unroll")                                                        \
    for (int mf = 0; mf < 4; ++mf)                                           \
      a8[mf] = *(const long long*)((lb) + (mf * 16 + l16) * 32 + ga);        \
    _Pragma("unroll")                                                        \
    for (int nf = 0; nf < 4; ++nf)                                           \
      b8[nf] = *(const long long*)((lb) + 2048 + (nf * 16 + l16) * 32 + ga); \
    _Pragma("unroll")                                                        \
    for (int mf = 0; mf < 4; ++mf)                                           \
      _Pragma("unroll")                                                      \
      for (int nf = 0; nf < 4; ++nf)                                         \
        acc[mf][nf] = __builtin_amdgcn_mfma_f32_16x16x32_fp8_fp8(            \
            a8[mf], b8[nf], acc[mf][nf], 0, 0, 0);                           \
  }

  char* b0 = smem;
  char* b1 = smem + 4096;
  char* b2 = smem + 8192;

  STGE(0, b0);
  STGE(1, b1);
#pragma unroll
  for (int s = 0; s < 14; ++s) {
    STGE(s + 2, b2);                                   // depth-2 prefetch
    asm volatile("s_waitcnt vmcnt(8)" ::: "memory");   // stage s landed
    __builtin_amdgcn_sched_barrier(0);
    COMPE(b0);
    char* tmp = b0; b0 = b1; b1 = b2; b2 = tmp;
  }
  asm volatile("s_waitcnt vmcnt(4)" ::: "memory");
  __builtin_amdgcn_sched_barrier(0);
  COMPE(b0);
  { char* tmp = b0; b0 = b1; b1 = b2; b2 = tmp; }
  asm volatile("s_waitcnt vmcnt(0)" ::: "memory");
  __builtin_amdgcn_sched_barrier(0);
  COMPE(b0);
#undef STGE
#undef COMPE

  // epilogue (wave-local, no barriers): exp2, unrounded rowsums, bf8 P
#pragma unroll
  for (int mf = 0; mf < 4; ++mf) {
#pragma unroll
    for (int r = 0; r < 4; ++r) {
      int row = mf * 16 + lg * 4 + r;                 // 0..63
      float rs = 0.f;
#pragma unroll
      for (int nf = 0; nf < 4; ++nf) {
        float p = __builtin_amdgcn_exp2f(acc[mf][nf][r] * SCEXP);
        rs += p;
        smem[row * 64 + nf * 16 + l16] = (char)f2bf8pos(p);
      }
      rs += __shfl_xor(rs, 1); rs += __shfl_xor(rs, 2);
      rs += __shfl_xor(rs, 4); rs += __shfl_xor(rs, 8);
      if (l16 == 0) atomicAdd(&dsum[m0 + row], rs);
    }
  }
  // copy-out 64x64 bf8 (wave-local LDS ordering; in-order DS pipe)
#pragma unroll
  for (int it = 0; it < 4; ++it) {
    int slot = it * 64 + l;
    int row = slot >> 2, g = slot & 3;
    uint4 v = *(const uint4*)(smem + row * 64 + g * 16);
    *(uint4*)(Pp + ((size_t)(m0 + row) * N_ + n0 + g * 16)) = v;
  }
}

// ============== pv8: out = x + vM8 P8^T / denom (fp8 x bf8 GEMM) ============
// Natural-layout A (vM8 e4m3) and B (P8 e5m2); BK=64 via 2x ds_read_b64.
__global__ __launch_bounds__(256, 4) void pv8(
    const u8* __restrict__ vM8, const u8* __restrict__ P8,
    const float* __restrict__ denom, const float* __restrict__ x,
    float* __restrict__ out)
{
  int fid = blockIdx.x;                 // 512 blocks
  int rid = (fid & 7) * 64 + (fid >> 3);
  int z = rid >> 7;
  int r7 = rid & 127;
  int n0 = (r7 >> 2) * 128;             // over N (P rows = q)
  int m0 = (r7 & 3) * 128;              // over C (vM rows)

  const u8* Ab = vM8 + (size_t)z * ((size_t)C_ * N_);
  const u8* Bb = P8 + (size_t)z * ((size_t)N_ * N_);
  const float* db = denom + (size_t)z * N_;
  const float* xb = x + (size_t)z * ((size_t)C_ * N_);
  float* ob = out + (size_t)z * ((size_t)C_ * N_);

  int t = threadIdx.x, w = t >> 6, l = t & 63;
  int wr = w >> 1, wc = w & 1;
  int l16 = l & 15, lg = l >> 4;

  __shared__ char smem[32768];          // 2 x (A 8KB + B 8KB)

  f32x4 acc[4][4] = {};
  // b64 read offsets for kk=0/1: granule (kk*2+(lg>>1)) ^ ((l16>>1)&3)
  int sxr = (l16 >> 1) & 3;
  int off0 = ((((lg >> 1) + 0) ^ sxr) << 4) | ((lg & 1) << 3);
  int off1 = ((((lg >> 1) + 2) ^ sxr) << 4) | ((lg & 1) << 3);

#define STGP(step, lb) {                                                     \
    size_t kb = (size_t)(step) * 64;                                         \
    _Pragma("unroll")                                                        \
    for (int i = 0; i < 2; ++i) {                                            \
      int s2 = i * 256 + t;                                                  \
      int row = s2 >> 2, g = s2 & 3;                                         \
      int sg = (g ^ ((row >> 1) & 3)) << 4;                                  \
      gld16((const char*)Ab + (size_t)(m0 + row) * N_ + kb + sg,             \
            (lb) + (size_t)s2 * 16);                                         \
      gld16((const char*)Bb + (size_t)(n0 + row) * N_ + kb + sg,             \
            (lb) + 8192 + (size_t)s2 * 16);                                  \
    }                                                                        \
  }

#define COMPP(lb) {                                                          \
    const char* Al = (lb);                                                   \
    const char* Bl = (lb) + 8192;                                            \
    long long a0[4], a1[4], c0v[4], c1v[4];                                  \
    _Pragma("unroll")                                                        \
    for (int mf = 0; mf < 4; ++mf) {                                         \
      int ro = (wr * 64 + mf * 16 + l16) * 64;                               \
      a0[mf] = *(const long long*)(Al + ro + off0);                          \
      a1[mf] = *(const long long*)(Al + ro + off1);                          \
    }                                                                        \
    _Pragma("unroll")                                                        \
    for (int nf = 0; nf < 4; ++nf) {                                         \
      int ro = (wc * 64 + nf * 16 + l16) * 64;                               \
      c0v[nf] = *(const long long*)(Bl + ro + off0);                         \
      c1v[nf] = *(const long long*)(Bl + ro + off1);                         \
    }                                                                        \
    _Pragma("unroll")                                                        \
    for (int mf = 0; mf < 4; ++mf)                                           \
      _Pragma("unroll")                                                      \
      for (int nf = 0; nf < 4; ++nf) {                                       \
        acc[mf][nf] = __builtin_amdgcn_mfma_f32_16x16x32_fp8_bf8(            \
            a0[mf], c0v[nf], acc[mf][nf], 0, 0, 0);                          \
        acc[mf][nf] = __builtin_amdgcn_mfma_f32_16x16x32_fp8_bf8(            \
            a1[mf], c1v[nf], acc[mf][nf], 0, 0, 0);                          \
      }                                                                      \
  }

  char* buf0 = smem;
  char* buf1 = smem + 16384;

  STGP(0, buf0);
#pragma unroll 2
  for (int s = 0; s < 64; ++s) {
    char* cb = (s & 1) ? buf1 : buf0;
    char* nb = (s & 1) ? buf0 : buf1;
    if (s < 63) {
      STGP(s + 1, nb);
      asm volatile("s_waitcnt vmcnt(4)" ::: "memory");
    } else {
      asm volatile("s_waitcnt vmcnt(0)" ::: "memory");
    }
    __builtin_amdgcn_s_barrier();
    __builtin_amdgcn_sched_barrier(0);
    COMPP(cb);
    __builtin_amdgcn_sched_barrier(0);
    __builtin_amdgcn_s_barrier();
  }
#undef STGP
#undef COMPP

  float rd[4];
#pragma unroll
  for (int nf = 0; nf < 4; ++nf)
    rd[nf] = 1.0f / db[n0 + wc * 64 + nf * 16 + l16];
#pragma unroll
  for (int mf = 0; mf < 4; ++mf) {
#pragma unroll
    for (int r = 0; r < 4; ++r) {
      int row = m0 + wr * 64 + mf * 16 + lg * 4 + r;
#pragma unroll
      for (int nf = 0; nf < 4; ++nf) {
        int col = n0 + wc * 64 + nf * 16 + l16;
        size_t o = (size_t)row * N_ + col;
        ob[o] = xb[o] + acc[mf][nf][r] * rd[nf];
      }
    }
  }
}

// ================== round-1 fallback path (tiny ws) =========================
__global__ __launch_bounds__(256) void gemm_abT(
    const u16* __restrict__ A, const u16* __restrict__ Bm,
    const float* __restrict__ bias, u16* __restrict__ out,
    int ldo, int bias_is_row)
{
  int w = threadIdx.x >> 6, l = threadIdx.x & 63;
  int l16 = l & 15, lg = l >> 4;
  int m0 = blockIdx.x * 128 + (w >> 1) * 64;
  int n0 = blockIdx.y * 128 + (w & 1) * 64;
  f32x4 acc[4][4] = {};
  const u16* Ab = A  + (size_t)(m0 + l16) * 512 + lg * 8;
  const u16* Bb = Bm + (size_t)(n0 + l16) * 512 + lg * 8;
  for (int kc = 0; kc < 512; kc += 32) {
    bf16x8 af[4], bf[4];
#pragma unroll
    for (int i = 0; i < 4; ++i) af[i] = ld16g(Ab + (size_t)(i * 16) * 512 + kc);
#pragma unroll
    for (int j = 0; j < 4; ++j) bf[j] = ld16g(Bb + (size_t)(j * 16) * 512 + kc);
#pragma unroll
    for (int i = 0; i < 4; ++i)
#pragma unroll
      for (int j = 0; j < 4; ++j)
        acc[i][j] = __builtin_amdgcn_mfma_f32_16x16x32_bf16(af[i], bf[j], acc[i][j], 0, 0, 0);
  }
#pragma unroll
  for (int i = 0; i < 4; ++i) {
#pragma unroll
    for (int j = 0; j < 4; ++j) {
      int col = n0 + j * 16 + l16;
#pragma unroll
      for (int r = 0; r < 4; ++r) {
        int row = m0 + i * 16 + lg * 4 + r;
        float v = acc[i][j][r] + (bias_is_row ? bias[row] : bias[col]);
        out[(size_t)row * ldo + col] = f2bf(v);
      }
    }
  }
}

#define NQ 32
#define NKB 64
__global__ __launch_bounds__(512) void attn_kernel(
    const u16* __restrict__ qT, const u16* __restrict__ kT, const u16* __restrict__ vM,
    const float* __restrict__ x, float* __restrict__ out)
{
  int b = blockIdx.y;
  int nq0 = blockIdx.x * NQ;
  const u16* qTb = qT + (size_t)b * N_ * C_;
  const u16* kTb = kT + (size_t)b * N_ * C_;
  const u16* vb  = vM + (size_t)b * C_ * N_;
  const float* xb = x + (size_t)b * C_ * N_;
  float* ob = out + (size_t)b * C_ * N_;

  int tid = threadIdx.x;
  int w = tid >> 6, l = tid & 63, l16 = l & 15, lg = l >> 4;
  int nqf = w & 1, nkf = w >> 1;
  int c0 = w * 64;

  __shared__ u16 qlds[32][520];
  __shared__ u16 Plds[32][72];
  __shared__ float dpart[32][16];
  __shared__ float dfin[32];

  for (int idx = tid; idx < 32 * 64; idx += 512) {
    int row = idx >> 6, cg = idx & 63;
    *(uint4*)&qlds[row][cg * 8] = *(const uint4*)(qTb + (size_t)(nq0 + row) * C_ + cg * 8);
  }
  __syncthreads();

  f32x4 acc[2][4] = {};
  float dreg = 0.f;
  int drow = tid >> 4, dcol = (tid & 15) * 4;

  for (int nk0 = 0; nk0 < N_; nk0 += NKB) {
    f32x4 s = {0.f, 0.f, 0.f, 0.f};
    const u16* krow = kTb + (size_t)(nk0 + nkf * 16 + l16) * C_ + lg * 8;
#pragma unroll 4
    for (int kc = 0; kc < 16; ++kc) {
      U16B tq; tq.u = *(const uint4*)&qlds[nqf * 16 + l16][kc * 32 + lg * 8];
      bf16x8 kf = ld16g(krow + kc * 32);
      s = __builtin_amdgcn_mfma_f32_16x16x32_bf16(tq.v, kf, s, 0, 0, 0);
    }
    __syncthreads();
#pragma unroll
    for (int r = 0; r < 4; ++r) {
      float p = __builtin_amdgcn_exp2f(s[r] * SCEXP);
      Plds[nqf * 16 + lg * 4 + r][nkf * 16 + l16] = f2bf(p);
    }
    __syncthreads();
#pragma unroll
    for (int r = 0; r < 4; ++r) dreg += bf2f(Plds[drow][dcol + r]);
#pragma unroll
    for (int kk = 0; kk < 2; ++kk) {
      bf16x8 pf[2];
#pragma unroll
      for (int i = 0; i < 2; ++i) {
        U16B t2; t2.u = *(const uint4*)&Plds[i * 16 + l16][kk * 32 + lg * 8];
        pf[i] = t2.v;
      }
#pragma unroll
      for (int j = 0; j < 4; ++j) {
        bf16x8 vf = ld16g(vb + (size_t)(c0 + j * 16 + l16) * N_ + nk0 + kk * 32 + lg * 8);
#pragma unroll
        for (int i = 0; i < 2; ++i)
          acc[i][j] = __builtin_amdgcn_mfma_f32_16x16x32_bf16(pf[i], vf, acc[i][j], 0, 0, 0);
      }
    }
  }

  dpart[drow][tid & 15] = dreg;
  __syncthreads();
  if (tid < 32) {
    float s2 = 0.f;
#pragma unroll
    for (int g = 0; g < 16; ++g) s2 += dpart[tid][g];
    dfin[tid] = s2;
  }
  __syncthreads();

#pragma unroll
  for (int i = 0; i < 2; ++i) {
    float dinv[4];
#pragma unroll
    for (int r = 0; r < 4; ++r) dinv[r] = 1.f / dfin[i * 16 + lg * 4 + r];
    int nbase = nq0 + i * 16 + lg * 4;
#pragma unroll
    for (int j = 0; j < 4; ++j) {
      int c = c0 + j * 16 + l16;
      float4 xv = *(const float4*)(xb + (size_t)c * N_ + nbase);
      float4 o;
      o.x = xv.x + acc[i][j][0] * dinv[0];
      o.y = xv.y + acc[i][j][1] * dinv[1];
      o.z = xv.z + acc[i][j][2] * dinv[2];
      o.w = xv.w + acc[i][j][3] * dinv[3];
      *(float4*)(ob + (size_t)c * N_ + nbase) = o;
    }
  }
}

extern "C" void kernel_launch(void* const* d_in, const int* in_sizes, int n_in,
                              void* d_out, int out_size, void* d_ws, size_t ws_size,
                              hipStream_t stream) {
  (void)in_sizes; (void)n_in; (void)out_size;
  const float* x  = (const float*)d_in[0];
  const float* wq = (const float*)d_in[1];
  const float* bq = (const float*)d_in[2];
  const float* wk = (const float*)d_in[3];
  const float* bk = (const float*)d_in[4];
  const float* wv = (const float*)d_in[5];
  const float* bv = (const float*)d_in[6];
  float* out = (float*)d_out;
  char* ws = (char*)d_ws;

  const size_t NC = (size_t)N_ * C_;        // 2097152 elems
  const size_t NEED = 136380416;

  if (ws_size >= NEED) {
    u16*   wbf_q = (u16*)(ws);              // wbf_k contiguous after (fused proj)
    u16*   wbf_k = (u16*)(ws + 524288);
    u16*   wbf_v = (u16*)(ws + 1048576);
    float* bqk   = (float*)(ws + 1572864);
    float* mu    = (float*)(ws + 1581056);
    float* rstd  = (float*)(ws + 1589248);
    u16*   hT    = (u16*)(ws + 1597440);    // 16.8 MB (B,N,C) bf16
    u8*    qk8   = (u8*)(ws + 18874368);    // 16.8 MB (B,N,1024) fp8 natural
    u8*    vM8   = (u8*)(ws + 52428800);    //  8.4 MB (B,C,N) fp8 natural
    float* denom = (float*)(ws + 69206016); // 64 KB
    u8*    P8    = (u8*)(ws + 69271552);    // 67.1 MB (B,N,N) bf8 natural

    cvt_w<<<256, 256, 0, stream>>>(wq, wbf_q);
    cvt_w<<<256, 256, 0, stream>>>(wk, wbf_k);
    cvt_w<<<256, 256, 0, stream>>>(wv, wbf_v);
    pack_bias<<<1, 1024, 0, stream>>>(bq, bk, bqk);
    inorm_stats<<<B_ * C_, 256, 0, stream>>>(x, mu, rstd);
    norm_transpose<<<dim3(N_ / 64, C_ / 64, B_), 256, 0, stream>>>(x, mu, rstd, hT);
    hipMemsetAsync(denom, 0, 4 * N_ * sizeof(float), stream);

    // fused q+k projection -> fp8 qk8 (B = [wq; wk] 1024x512, ldo=1024)
    gemm128<EPI_QK8><<<dim3(32, 8, 4), 256, 0, stream>>>(
        hT, wbf_q, bqk, qk8, 512, 512, 512, 1024, (long)NC, 0, (long)N_ * 1024);
    // v projection -> vM8 (C,N) fp8
    gemm128<EPI_V8><<<dim3(4, 32, 4), 256, 0, stream>>>(
        wbf_v, hT, bv, vM8, 512, 512, 512, 4096, 0, (long)NC, (long)NC);

    // P8 = bf8(exp(scale * q k^T)), unrounded rowsums -> denom
    exp_wave<<<16384, 64, 0, stream>>>(qk8, denom, P8);

    // out = x + vM8 P8^T / denom
    pv8<<<512, 256, 0, stream>>>(vM8, P8, denom, x, out);
  } else {
    // ---- fallback: round-1 path (65.5 MB ws) ----
    u16*   wbf_q = (u16*)(ws);
    u16*   wbf_k = (u16*)(ws + 524288);
    u16*   wbf_v = (u16*)(ws + 1048576);
    float* mu    = (float*)(ws + 1572864);
    float* rstd  = (float*)(ws + 1581056);
    u16*   hT    = (u16*)(ws + 1589248);
    u16*   qT    = (u16*)(ws + 18366464);
    u16*   kT    = (u16*)(ws + 35143680);
    u16*   vM    = (u16*)(ws + 51920896);

    cvt_w<<<256, 256, 0, stream>>>(wq, wbf_q);
    cvt_w<<<256, 256, 0, stream>>>(wk, wbf_k);
    cvt_w<<<256, 256, 0, stream>>>(wv, wbf_v);
    inorm_stats<<<B_ * C_, 256, 0, stream>>>(x, mu, rstd);
    norm_transpose<<<dim3(N_ / 64, C_ / 64, B_), 256, 0, stream>>>(x, mu, rstd, hT);

    for (int b = 0; b < B_; ++b) {
      const u16* hTb = hT + (size_t)b * NC;
      u16* qTb = qT + (size_t)b * NC;
      u16* kTb = kT + (size_t)b * NC;
      u16* vMb = vM + (size_t)b * NC;
      gemm_abT<<<dim3(N_ / 128, C_ / 128), 256, 0, stream>>>(hTb, wbf_q, bq, qTb, C_, 0);
      gemm_abT<<<dim3(N_ / 128, C_ / 128), 256, 0, stream>>>(hTb, wbf_k, bk, kTb, C_, 0);
      gemm_abT<<<dim3(C_ / 128, N_ / 128), 256, 0, stream>>>(wbf_v, hTb, bv, vMb, N_, 1);
    }
    attn_kernel<<<dim3(N_ / NQ, B_), 512, 0, stream>>>(qT, kT, vM, x, out);
  }
}

// Round 12
// 222.474 us; speedup vs baseline: 1.2910x; 1.2910x over previous
//
#include <hip/hip_runtime.h>
#include <hip/hip_bf16.h>
#include <cstdint>

#define B_ 4
#define C_ 512
#define N_ 4096

typedef unsigned short u16;
typedef unsigned char u8;
typedef __bf16 bf16x8 __attribute__((ext_vector_type(8)));
typedef float f32x4 __attribute__((ext_vector_type(4)));

union U16B { uint4 u; bf16x8 v; };

__device__ __forceinline__ bf16x8 ld16g(const u16* p) {
  U16B t; t.u = *(const uint4*)p; return t.v;
}

__device__ __forceinline__ u16 f2bf(float f) {
  uint32_t u = __builtin_bit_cast(uint32_t, f);
  u = (u + 0x7FFFu + ((u >> 16) & 1u)) >> 16;
  return (u16)u;
}
__device__ __forceinline__ float bf2f(u16 h) {
  uint32_t u = ((uint32_t)h) << 16;
  return __builtin_bit_cast(float, u);
}

// f32 -> fp8 e4m3fn (OCP), RNE (validated r8-r10).
__device__ __forceinline__ u8 f2fp8(float f) {
  uint32_t u = __builtin_bit_cast(uint32_t, f);
  uint32_t s = (u >> 24) & 0x80u;
  uint32_t a = u & 0x7FFFFFFFu;
  if (a >= 0x43700000u) return (u8)(s | 0x7E);
  if (a < 0x3C800000u) {
    float af = __builtin_bit_cast(float, a);
    int m = (int)(af * 512.0f + 0.5f);
    return (u8)(s | (uint32_t)m);
  }
  uint32_t r = (a + 0x7FFFFu + ((a >> 20) & 1u)) >> 20;
  return (u8)(s | (r - (120u << 3)));
}

// f32 -> bf8 e5m2 for positive values: f16 cvt + RNE truncate (validated r11)
__device__ __forceinline__ u8 f2bf8pos(float f) {
  _Float16 h = (_Float16)f;
  u16 hb = __builtin_bit_cast(unsigned short, h);
  hb = (u16)(hb + 0x7Fu + ((hb >> 8) & 1u));
  return (u8)(hb >> 8);
}

typedef const __attribute__((address_space(1))) uint32_t* gas_p;
typedef __attribute__((address_space(3))) uint32_t* las_p;
__device__ __forceinline__ void gld16(const void* g, void* l) {
  __builtin_amdgcn_global_load_lds((gas_p)g, (las_p)l, 16, 0, 0);
}

#define SCEXP 0.06376149809794171f  /* 512^-0.5 * log2(e) */

// ---------------- K0: f32 -> bf16 weight convert (512x512 each) -------------
__global__ __launch_bounds__(256) void cvt_w(const float* __restrict__ w, u16* __restrict__ o) {
  int i = blockIdx.x * 256 + threadIdx.x;
  float4 v = ((const float4*)w)[i];
  ushort4 r;
  r.x = f2bf(v.x); r.y = f2bf(v.y); r.z = f2bf(v.z); r.w = f2bf(v.w);
  ((ushort4*)o)[i] = r;
}

// ---------------- K0b: pack [bq; bk] -> 1024 f32 ----------------------------
__global__ __launch_bounds__(1024) void pack_bias(const float* __restrict__ bq,
    const float* __restrict__ bk, float* __restrict__ o) {
  int i = threadIdx.x;
  o[i] = (i < 512) ? bq[i] : bk[i - 512];
}

// ---------------- K1: instance-norm stats per (b,c) over 4096 ---------------
__global__ __launch_bounds__(256) void inorm_stats(const float* __restrict__ x,
    float* __restrict__ mu, float* __restrict__ rstd) {
  int bc = blockIdx.x;
  const float4* p = (const float4*)(x + (size_t)bc * N_);
  float s = 0.f, ss = 0.f;
  for (int i = threadIdx.x; i < N_ / 4; i += 256) {
    float4 v = p[i];
    s  += v.x + v.y + v.z + v.w;
    ss += v.x * v.x + v.y * v.y + v.z * v.z + v.w * v.w;
  }
#pragma unroll
  for (int off = 32; off > 0; off >>= 1) {
    s  += __shfl_down(s, off);
    ss += __shfl_down(ss, off);
  }
  __shared__ float as_[4], ass_[4];
  if ((threadIdx.x & 63) == 0) { as_[threadIdx.x >> 6] = s; ass_[threadIdx.x >> 6] = ss; }
  __syncthreads();
  if (threadIdx.x == 0) {
    float S  = as_[0] + as_[1] + as_[2] + as_[3];
    float SS = ass_[0] + ass_[1] + ass_[2] + ass_[3];
    float m  = S * (1.f / N_);
    float var = SS * (1.f / N_) - m * m;
    mu[bc] = m;
    rstd[bc] = rsqrtf(var + 1e-5f);
  }
}

// ---------------- K2: normalize + transpose -> hT (B,N,C) bf16 --------------
__global__ __launch_bounds__(256) void norm_transpose(const float* __restrict__ x,
    const float* __restrict__ mu, const float* __restrict__ rstd, u16* __restrict__ hT) {
  __shared__ u16 tile[64][66];
  int b = blockIdx.z, c0 = blockIdx.y * 64, n0 = blockIdx.x * 64;
  int tn = threadIdx.x & 63, t4 = threadIdx.x >> 6;
  const float* xb = x + ((size_t)b * C_ + c0) * N_ + n0;
#pragma unroll
  for (int it = 0; it < 16; ++it) {
    int c = t4 + it * 4;
    float m  = mu[b * C_ + c0 + c];
    float rs = rstd[b * C_ + c0 + c];
    tile[c][tn] = f2bf((xb[(size_t)c * N_ + tn] - m) * rs);
  }
  __syncthreads();
  u16* hTb = hT + ((size_t)b * N_ + n0) * C_ + c0;
#pragma unroll
  for (int it = 0; it < 16; ++it) {
    int n = t4 + it * 4;
    hTb[(size_t)n * C_ + tn] = tile[tn][n];
  }
}

// ============== gemm128: BK=64 dbuf projections -> fp8 out ==================
// EPI_QK8: bias[col] -> fp8, per-64-col-group K-perm for exp8's C-dim granules
//   (col w6 -> ((w6>>3)&3)*16 + ((w6>>5)&1)*8 + (w6&7); r8-proven)
// EPI_V8: bias[row] -> fp8, per-64-col-group kmap pos=(l16<<2)|nf for key-dim
//   (MUST match exp8's P kmap; packed u32 stores, XOR-block anti-conflict)
#define EPI_QK8  2
#define EPI_V8   3

template<int EPI>
__global__ __launch_bounds__(256) void gemm128(
    const u16* __restrict__ A, const u16* __restrict__ B,
    const float* __restrict__ aux, void* __restrict__ Out,
    int klen, int lda, int ldb, int ldo,
    long sAz, long sBz, long sOz)
{
  int z = blockIdx.z;
  const u16* Ab = A + (size_t)z * sAz;
  const u16* Bb = B + (size_t)z * sBz;
  int m0 = blockIdx.x * 128, n0 = blockIdx.y * 128;
  int t = threadIdx.x, w = t >> 6, l = t & 63;
  int wr = w >> 1, wc = w & 1;
  int l16 = l & 15, lg = l >> 4;

  __shared__ char smem[65536];

  int srow = t >> 3;
  int scol = ((t & 7) << 4) ^ ((srow & 7) << 4);
  size_t ldaB = (size_t)lda * 2, ldbB = (size_t)ldb * 2;

  f32x4 acc[4][4] = {};
  int nsteps = klen >> 6;

#define STAGE(step, d) {                                                     \
    size_t kbyte = (size_t)(step) * 128 + scol;                              \
    char* lb = smem + (d) * 32768;                                           \
    _Pragma("unroll")                                                        \
    for (int i = 0; i < 4; ++i) {                                            \
      int row = i * 32 + srow;                                               \
      gld16((const char*)Ab + (size_t)(m0 + row) * ldaB + kbyte,             \
            lb + (size_t)(i * 256 + t) * 16);                                \
      gld16((const char*)Bb + (size_t)(n0 + row) * ldbB + kbyte,             \
            lb + 16384 + (size_t)(i * 256 + t) * 16);                        \
    }                                                                        \
  }

  STAGE(0, 0);
  __syncthreads();
  int cur = 0;
  int sw = (l16 & 7) << 4;
  for (int s = 0; s < nsteps; ++s) {
    if (s + 1 < nsteps) STAGE(s + 1, cur ^ 1);
    const char* Al = smem + cur * 32768;
    const char* Bl = Al + 16384;
#pragma unroll
    for (int kc = 0; kc < 2; ++kc) {
      int cb = (kc * 64 + lg * 16) ^ sw;
      bf16x8 af[4], bf[4];
#pragma unroll
      for (int mf = 0; mf < 4; ++mf)
        af[mf] = *(const bf16x8*)(Al + (wr * 64 + mf * 16 + l16) * 128 + cb);
#pragma unroll
      for (int nf = 0; nf < 4; ++nf)
        bf[nf] = *(const bf16x8*)(Bl + (wc * 64 + nf * 16 + l16) * 128 + cb);
#pragma unroll
      for (int mf = 0; mf < 4; ++mf)
#pragma unroll
        for (int nf = 0; nf < 4; ++nf)
          acc[mf][nf] = __builtin_amdgcn_mfma_f32_16x16x32_bf16(af[mf], bf[nf], acc[mf][nf], 0, 0, 0);
    }
    __syncthreads();
    cur ^= 1;
  }
#undef STAGE

  u8* ob = (u8*)Out + (size_t)z * sOz;
  char* sb = smem;
  if constexpr (EPI == EPI_QK8) {
    float bc[4];
#pragma unroll
    for (int nf = 0; nf < 4; ++nf) bc[nf] = aux[n0 + wc * 64 + nf * 16 + l16];
#pragma unroll
    for (int mf = 0; mf < 4; ++mf) {
#pragma unroll
      for (int r = 0; r < 4; ++r) {
        int rowl = wr * 64 + mf * 16 + lg * 4 + r;
#pragma unroll
        for (int nf = 0; nf < 4; ++nf) {
          int cl = wc * 64 + nf * 16 + l16;
          int w6 = cl & 63;
          int clp = (cl & 64) | (((w6 >> 3) & 3) * 16) | (((w6 >> 5) & 1) * 8) | (w6 & 7);
          sb[rowl * 128 + clp] = (char)f2fp8(acc[mf][nf][r] + bc[nf]);
        }
      }
    }
    __syncthreads();
#pragma unroll
    for (int it = 0; it < 4; ++it) {
      int idx = it * 256 + t;
      int row = idx >> 3, seg = idx & 7;
      *(uint4*)(ob + (size_t)(m0 + row) * ldo + n0 + seg * 16) =
          *(const uint4*)(sb + row * 128 + seg * 16);
    }
  } else {  // EPI_V8: packed u32, kmap pos=(l16<<2)|nf, XOR-block by (row>>2)&1
#pragma unroll
    for (int mf = 0; mf < 4; ++mf) {
#pragma unroll
      for (int r = 0; r < 4; ++r) {
        int rowl = wr * 64 + mf * 16 + lg * 4 + r;   // 0..127
        float brow = aux[m0 + rowl];
        uint32_t pk = 0;
#pragma unroll
        for (int nf = 0; nf < 4; ++nf)
          pk |= (uint32_t)f2fp8(acc[mf][nf][r] + brow) << (8 * nf);
        int blk = (wc ^ ((rowl >> 2) & 1)) << 6;
        *(uint32_t*)(sb + rowl * 128 + blk + l16 * 4) = pk;
      }
    }
    __syncthreads();
#pragma unroll
    for (int it = 0; it < 4; ++it) {
      int idx = it * 256 + t;
      int row = idx >> 3, seg = idx & 7;
      int blk = ((seg >> 2) ^ ((row >> 2) & 1)) << 6;
      *(uint4*)(ob + (size_t)(m0 + row) * ldo + n0 + seg * 16) =
          *(const uint4*)(sb + row * 128 + blk + (seg & 3) * 16);
    }
  }
}

// ============== exp8: 128x256 tile, fp8, BK=64, dbuf + vmcnt(3) =============
// r8-proven core. P out = bf8 e5m2 with kmap pos=(l16<<2)|nf per 64-key group
// (matches EPI_V8's vM8 kmap -> pv8 contracts by position). Packed u32 stores.
__global__ __launch_bounds__(512, 3) void exp8(
    const u8* __restrict__ qk8, float* __restrict__ dsumAll, u8* __restrict__ Pall)
{
  // XCD chunk + 8x8 supertile
  int fid = blockIdx.x;                  // 2048 blocks
  int rid = (fid & 7) * 256 + (fid >> 3);
  int z = rid >> 9;
  int r9 = rid & 511;
  int c2 = r9 >> 8;
  int r8 = r9 & 255;
  int sm = r8 >> 6, w6s = r8 & 63;
  int m0 = (c2 * 16 + (sm >> 1) * 8 + (w6s >> 3)) * 128;
  int n0 = ((sm & 1) * 8 + (w6s & 7)) * 256;

  const u8* Ab = qk8 + (size_t)z * ((size_t)N_ * 1024);        // q half
  const u8* Bb = Ab + 512;                                     // k half
  float* dsum = dsumAll + (size_t)z * N_;
  u8* Pp = Pall + (size_t)z * (size_t)N_ * N_;

  int t = threadIdx.x, w = t >> 6, l = t & 63;
  int wr = w >> 2, wc = w & 3;           // 2 m-halves x 4 n-quarters
  int l16 = l & 15, lg = l >> 4;

  __shared__ char smem[49152];           // dbuf 2x24KB; epilogue uses 32KB

  f32x4 acc[4][4] = {};
  int rg = ((lg ^ ((l16 >> 1) & 3)) & 3) << 4;   // conflict-free (r6-verified)

#define STG8(step, lb) {                                                     \
    size_t kb = (size_t)(step) * 64;                                         \
    {                                                                        \
      int row = t >> 2, g = t & 3;                                           \
      int sg = (g ^ ((row >> 1) & 3)) << 4;                                  \
      gld16((const char*)Ab + (size_t)(m0 + row) * 1024 + kb + sg,           \
            (lb) + (size_t)t * 16);                                          \
    }                                                                        \
    _Pragma("unroll")                                                        \
    for (int i = 0; i < 2; ++i) {                                            \
      int s2 = i * 512 + t;                                                  \
      int row = s2 >> 2, g = s2 & 3;                                         \
      int sg = (g ^ ((row >> 1) & 3)) << 4;                                  \
      gld16((const char*)Bb + (size_t)(n0 + row) * 1024 + kb + sg,           \
            (lb) + 8192 + (size_t)s2 * 16);                                  \
    }                                                                        \
  }

#define COMP8(lb) {                                                          \
    const char* Al = (lb);                                                   \
    const char* Bl = (lb) + 8192;                                            \
    uint4 af[4], bf[4];                                                      \
    _Pragma("unroll")                                                        \
    for (int mf = 0; mf < 4; ++mf)                                           \
      af[mf] = *(const uint4*)(Al + (wr * 64 + mf * 16 + l16) * 64 + rg);    \
    _Pragma("unroll")                                                        \
    for (int nf = 0; nf < 4; ++nf)                                           \
      bf[nf] = *(const uint4*)(Bl + (wc * 64 + nf * 16 + l16) * 64 + rg);    \
    _Pragma("unroll")                                                        \
    for (int kk = 0; kk < 2; ++kk) {                                         \
      _Pragma("unroll")                                                      \
      for (int mf = 0; mf < 4; ++mf) {                                       \
        long long a8 = ((long long)(kk ? af[mf].w : af[mf].y) << 32) |       \
                       (unsigned int)(kk ? af[mf].z : af[mf].x);             \
        _Pragma("unroll")                                                    \
        for (int nf = 0; nf < 4; ++nf) {                                     \
          long long b8 = ((long long)(kk ? bf[nf].w : bf[nf].y) << 32) |     \
                         (unsigned int)(kk ? bf[nf].z : bf[nf].x);           \
          acc[mf][nf] = __builtin_amdgcn_mfma_f32_16x16x32_fp8_fp8(          \
              a8, b8, acc[mf][nf], 0, 0, 0);                                 \
        }                                                                    \
      }                                                                      \
    }                                                                        \
  }

  char* buf0 = smem;
  char* buf1 = smem + 24576;

  STG8(0, buf0);
#pragma unroll
  for (int s = 0; s < 8; ++s) {
    char* cb = (s & 1) ? buf1 : buf0;
    char* nb = (s & 1) ? buf0 : buf1;
    if (s < 7) {
      STG8(s + 1, nb);
      asm volatile("s_waitcnt vmcnt(3)" ::: "memory");
    } else {
      asm volatile("s_waitcnt vmcnt(0)" ::: "memory");
    }
    __builtin_amdgcn_s_barrier();
    __builtin_amdgcn_sched_barrier(0);
    COMP8(cb);
    __builtin_amdgcn_sched_barrier(0);
    __builtin_amdgcn_s_barrier();
  }
#undef STG8
#undef COMP8

  // epilogue: exp2, unrounded rowsums, e5m2 packed u32 (kmap), line stores
#pragma unroll
  for (int mf = 0; mf < 4; ++mf) {
#pragma unroll
    for (int r = 0; r < 4; ++r) {
      int row = wr * 64 + mf * 16 + lg * 4 + r;      // 0..127; (row>>2)&3 == lg
      float rs = 0.f;
      uint32_t pk = 0;
#pragma unroll
      for (int nf = 0; nf < 4; ++nf) {
        float p = __builtin_amdgcn_exp2f(acc[mf][nf][r] * SCEXP);
        rs += p;
        pk |= (uint32_t)f2bf8pos(p) << (8 * nf);
      }
      int blk = (wc ^ lg) << 6;
      *(uint32_t*)(smem + row * 256 + blk + l16 * 4) = pk;
      rs += __shfl_xor(rs, 1); rs += __shfl_xor(rs, 2);
      rs += __shfl_xor(rs, 4); rs += __shfl_xor(rs, 8);
      if (l16 == 0) atomicAdd(&dsum[m0 + row], rs);
    }
  }
  __syncthreads();
#pragma unroll
  for (int it = 0; it < 4; ++it) {
    int idx = it * 512 + t;
    int row = idx >> 4, seg = idx & 15;
    int blk = ((seg >> 2) ^ ((row >> 2) & 3)) << 6;
    *(uint4*)(Pp + ((size_t)(m0 + row) * N_ + n0 + seg * 16)) =
        *(const uint4*)(smem + row * 256 + blk + (seg & 3) * 16);
  }
}

// ============== pv8: out = x + vM8 P8^T / denom (e4m3 x e5m2 GEMM) ==========
// A/B both kmapped identically per 64-key group -> positional contraction OK.
__global__ __launch_bounds__(256, 4) void pv8(
    const u8* __restrict__ vM8, const u8* __restrict__ P8,
    const float* __restrict__ denom, const float* __restrict__ x,
    float* __restrict__ out)
{
  int fid = blockIdx.x;                 // 512 blocks
  int rid = (fid & 7) * 64 + (fid >> 3);
  int z = rid >> 7;
  int r7 = rid & 127;
  int n0 = (r7 >> 2) * 128;             // over N (P rows = q)
  int m0 = (r7 & 3) * 128;              // over C (vM rows)

  const u8* Ab = vM8 + (size_t)z * ((size_t)C_ * N_);
  const u8* Bb = P8 + (size_t)z * ((size_t)N_ * N_);
  const float* db = denom + (size_t)z * N_;
  const float* xb = x + (size_t)z * ((size_t)C_ * N_);
  float* ob = out + (size_t)z * ((size_t)C_ * N_);

  int t = threadIdx.x, w = t >> 6, l = t & 63;
  int wr = w >> 1, wc = w & 1;
  int l16 = l & 15, lg = l >> 4;

  __shared__ char smem[32768];          // 2 x (A 8KB + B 8KB)

  f32x4 acc[4][4] = {};
  int rg = ((lg ^ ((l16 >> 1) & 3)) & 3) << 4;

#define STGP(step, lb) {                                                     \
    size_t kb = (size_t)(step) * 64;                                         \
    _Pragma("unroll")                                                        \
    for (int i = 0; i < 2; ++i) {                                            \
      int s2 = i * 256 + t;                                                  \
      int row = s2 >> 2, g = s2 & 3;                                         \
      int sg = (g ^ ((row >> 1) & 3)) << 4;                                  \
      gld16((const char*)Ab + (size_t)(m0 + row) * N_ + kb + sg,             \
            (lb) + (size_t)s2 * 16);                                         \
      gld16((const char*)Bb + (size_t)(n0 + row) * N_ + kb + sg,             \
            (lb) + 8192 + (size_t)s2 * 16);                                  \
    }                                                                        \
  }

#define COMPP(lb) {                                                          \
    const char* Al = (lb);                                                   \
    const char* Bl = (lb) + 8192;                                            \
    uint4 af[4], bf[4];                                                      \
    _Pragma("unroll")                                                        \
    for (int mf = 0; mf < 4; ++mf)                                           \
      af[mf] = *(const uint4*)(Al + (wr * 64 + mf * 16 + l16) * 64 + rg);    \
    _Pragma("unroll")                                                        \
    for (int nf = 0; nf < 4; ++nf)                                           \
      bf[nf] = *(const uint4*)(Bl + (wc * 64 + nf * 16 + l16) * 64 + rg);    \
    _Pragma("unroll")                                                        \
    for (int kk = 0; kk < 2; ++kk) {                                         \
      _Pragma("unroll")                                                      \
      for (int mf = 0; mf < 4; ++mf) {                                       \
        long long a8 = ((long long)(kk ? af[mf].w : af[mf].y) << 32) |       \
                       (unsigned int)(kk ? af[mf].z : af[mf].x);             \
        _Pragma("unroll")                                                    \
        for (int nf = 0; nf < 4; ++nf) {                                     \
          long long b8 = ((long long)(kk ? bf[nf].w : bf[nf].y) << 32) |     \
                         (unsigned int)(kk ? bf[nf].z : bf[nf].x);           \
          acc[mf][nf] = __builtin_amdgcn_mfma_f32_16x16x32_fp8_bf8(          \
              a8, b8, acc[mf][nf], 0, 0, 0);                                 \
        }                                                                    \
      }                                                                      \
    }                                                                        \
  }

  char* buf0 = smem;
  char* buf1 = smem + 16384;

  STGP(0, buf0);
#pragma unroll 2
  for (int s = 0; s < 64; ++s) {
    char* cb = (s & 1) ? buf1 : buf0;
    char* nb = (s & 1) ? buf0 : buf1;
    if (s < 63) {
      STGP(s + 1, nb);
      asm volatile("s_waitcnt vmcnt(4)" ::: "memory");
    } else {
      asm volatile("s_waitcnt vmcnt(0)" ::: "memory");
    }
    __builtin_amdgcn_s_barrier();
    __builtin_amdgcn_sched_barrier(0);
    COMPP(cb);
    __builtin_amdgcn_sched_barrier(0);
    __builtin_amdgcn_s_barrier();
  }
#undef STGP
#undef COMPP

  float rd[4];
#pragma unroll
  for (int nf = 0; nf < 4; ++nf)
    rd[nf] = 1.0f / db[n0 + wc * 64 + nf * 16 + l16];
#pragma unroll
  for (int mf = 0; mf < 4; ++mf) {
#pragma unroll
    for (int r = 0; r < 4; ++r) {
      int row = m0 + wr * 64 + mf * 16 + lg * 4 + r;
#pragma unroll
      for (int nf = 0; nf < 4; ++nf) {
        int col = n0 + wc * 64 + nf * 16 + l16;
        size_t o = (size_t)row * N_ + col;
        ob[o] = xb[o] + acc[mf][nf][r] * rd[nf];
      }
    }
  }
}

// ================== round-1 fallback path (tiny ws) =========================
__global__ __launch_bounds__(256) void gemm_abT(
    const u16* __restrict__ A, const u16* __restrict__ Bm,
    const float* __restrict__ bias, u16* __restrict__ out,
    int ldo, int bias_is_row)
{
  int w = threadIdx.x >> 6, l = threadIdx.x & 63;
  int l16 = l & 15, lg = l >> 4;
  int m0 = blockIdx.x * 128 + (w >> 1) * 64;
  int n0 = blockIdx.y * 128 + (w & 1) * 64;
  f32x4 acc[4][4] = {};
  const u16* Ab = A  + (size_t)(m0 + l16) * 512 + lg * 8;
  const u16* Bb = Bm + (size_t)(n0 + l16) * 512 + lg * 8;
  for (int kc = 0; kc < 512; kc += 32) {
    bf16x8 af[4], bf[4];
#pragma unroll
    for (int i = 0; i < 4; ++i) af[i] = ld16g(Ab + (size_t)(i * 16) * 512 + kc);
#pragma unroll
    for (int j = 0; j < 4; ++j) bf[j] = ld16g(Bb + (size_t)(j * 16) * 512 + kc);
#pragma unroll
    for (int i = 0; i < 4; ++i)
#pragma unroll
      for (int j = 0; j < 4; ++j)
        acc[i][j] = __builtin_amdgcn_mfma_f32_16x16x32_bf16(af[i], bf[j], acc[i][j], 0, 0, 0);
  }
#pragma unroll
  for (int i = 0; i < 4; ++i) {
#pragma unroll
    for (int j = 0; j < 4; ++j) {
      int col = n0 + j * 16 + l16;
#pragma unroll
      for (int r = 0; r < 4; ++r) {
        int row = m0 + i * 16 + lg * 4 + r;
        float v = acc[i][j][r] + (bias_is_row ? bias[row] : bias[col]);
        out[(size_t)row * ldo + col] = f2bf(v);
      }
    }
  }
}

#define NQ 32
#define NKB 64
__global__ __launch_bounds__(512) void attn_kernel(
    const u16* __restrict__ qT, const u16* __restrict__ kT, const u16* __restrict__ vM,
    const float* __restrict__ x, float* __restrict__ out)
{
  int b = blockIdx.y;
  int nq0 = blockIdx.x * NQ;
  const u16* qTb = qT + (size_t)b * N_ * C_;
  const u16* kTb = kT + (size_t)b * N_ * C_;
  const u16* vb  = vM + (size_t)b * C_ * N_;
  const float* xb = x + (size_t)b * C_ * N_;
  float* ob = out + (size_t)b * C_ * N_;

  int tid = threadIdx.x;
  int w = tid >> 6, l = tid & 63, l16 = l & 15, lg = l >> 4;
  int nqf = w & 1, nkf = w >> 1;
  int c0 = w * 64;

  __shared__ u16 qlds[32][520];
  __shared__ u16 Plds[32][72];
  __shared__ float dpart[32][16];
  __shared__ float dfin[32];

  for (int idx = tid; idx < 32 * 64; idx += 512) {
    int row = idx >> 6, cg = idx & 63;
    *(uint4*)&qlds[row][cg * 8] = *(const uint4*)(qTb + (size_t)(nq0 + row) * C_ + cg * 8);
  }
  __syncthreads();

  f32x4 acc[2][4] = {};
  float dreg = 0.f;
  int drow = tid >> 4, dcol = (tid & 15) * 4;

  for (int nk0 = 0; nk0 < N_; nk0 += NKB) {
    f32x4 s = {0.f, 0.f, 0.f, 0.f};
    const u16* krow = kTb + (size_t)(nk0 + nkf * 16 + l16) * C_ + lg * 8;
#pragma unroll 4
    for (int kc = 0; kc < 16; ++kc) {
      U16B tq; tq.u = *(const uint4*)&qlds[nqf * 16 + l16][kc * 32 + lg * 8];
      bf16x8 kf = ld16g(krow + kc * 32);
      s = __builtin_amdgcn_mfma_f32_16x16x32_bf16(tq.v, kf, s, 0, 0, 0);
    }
    __syncthreads();
#pragma unroll
    for (int r = 0; r < 4; ++r) {
      float p = __builtin_amdgcn_exp2f(s[r] * SCEXP);
      Plds[nqf * 16 + lg * 4 + r][nkf * 16 + l16] = f2bf(p);
    }
    __syncthreads();
#pragma unroll
    for (int r = 0; r < 4; ++r) dreg += bf2f(Plds[drow][dcol + r]);
#pragma unroll
    for (int kk = 0; kk < 2; ++kk) {
      bf16x8 pf[2];
#pragma unroll
      for (int i = 0; i < 2; ++i) {
        U16B t2; t2.u = *(const uint4*)&Plds[i * 16 + l16][kk * 32 + lg * 8];
        pf[i] = t2.v;
      }
#pragma unroll
      for (int j = 0; j < 4; ++j) {
        bf16x8 vf = ld16g(vb + (size_t)(c0 + j * 16 + l16) * N_ + nk0 + kk * 32 + lg * 8);
#pragma unroll
        for (int i = 0; i < 2; ++i)
          acc[i][j] = __builtin_amdgcn_mfma_f32_16x16x32_bf16(pf[i], vf, acc[i][j], 0, 0, 0);
      }
    }
  }

  dpart[drow][tid & 15] = dreg;
  __syncthreads();
  if (tid < 32) {
    float s2 = 0.f;
#pragma unroll
    for (int g = 0; g < 16; ++g) s2 += dpart[tid][g];
    dfin[tid] = s2;
  }
  __syncthreads();

#pragma unroll
  for (int i = 0; i < 2; ++i) {
    float dinv[4];
#pragma unroll
    for (int r = 0; r < 4; ++r) dinv[r] = 1.f / dfin[i * 16 + lg * 4 + r];
    int nbase = nq0 + i * 16 + lg * 4;
#pragma unroll
    for (int j = 0; j < 4; ++j) {
      int c = c0 + j * 16 + l16;
      float4 xv = *(const float4*)(xb + (size_t)c * N_ + nbase);
      float4 o;
      o.x = xv.x + acc[i][j][0] * dinv[0];
      o.y = xv.y + acc[i][j][1] * dinv[1];
      o.z = xv.z + acc[i][j][2] * dinv[2];
      o.w = xv.w + acc[i][j][3] * dinv[3];
      *(float4*)(ob + (size_t)c * N_ + nbase) = o;
    }
  }
}

extern "C" void kernel_launch(void* const* d_in, const int* in_sizes, int n_in,
                              void* d_out, int out_size, void* d_ws, size_t ws_size,
                              hipStream_t stream) {
  (void)in_sizes; (void)n_in; (void)out_size;
  const float* x  = (const float*)d_in[0];
  const float* wq = (const float*)d_in[1];
  const float* bq = (const float*)d_in[2];
  const float* wk = (const float*)d_in[3];
  const float* bk = (const float*)d_in[4];
  const float* wv = (const float*)d_in[5];
  const float* bv = (const float*)d_in[6];
  float* out = (float*)d_out;
  char* ws = (char*)d_ws;

  const size_t NC = (size_t)N_ * C_;        // 2097152 elems
  const size_t NEED = 136380416;

  if (ws_size >= NEED) {
    u16*   wbf_q = (u16*)(ws);              // wbf_k contiguous after (fused proj)
    u16*   wbf_k = (u16*)(ws + 524288);
    u16*   wbf_v = (u16*)(ws + 1048576);
    float* bqk   = (float*)(ws + 1572864);
    float* mu    = (float*)(ws + 1581056);
    float* rstd  = (float*)(ws + 1589248);
    u16*   hT    = (u16*)(ws + 1597440);    // 16.8 MB (B,N,C) bf16
    u8*    qk8   = (u8*)(ws + 18874368);    // 16.8 MB (B,N,1024) fp8, C-perm
    u8*    vM8   = (u8*)(ws + 52428800);    //  8.4 MB (B,C,N) fp8, key-kmap
    float* denom = (float*)(ws + 69206016); // 64 KB
    u8*    P8    = (u8*)(ws + 69271552);    // 67.1 MB (B,N,N) bf8, key-kmap

    cvt_w<<<256, 256, 0, stream>>>(wq, wbf_q);
    cvt_w<<<256, 256, 0, stream>>>(wk, wbf_k);
    cvt_w<<<256, 256, 0, stream>>>(wv, wbf_v);
    pack_bias<<<1, 1024, 0, stream>>>(bq, bk, bqk);
    inorm_stats<<<B_ * C_, 256, 0, stream>>>(x, mu, rstd);
    norm_transpose<<<dim3(N_ / 64, C_ / 64, B_), 256, 0, stream>>>(x, mu, rstd, hT);
    hipMemsetAsync(denom, 0, 4 * N_ * sizeof(float), stream);

    // fused q+k projection -> fp8 qk8 (B = [wq; wk] 1024x512, ldo=1024)
    gemm128<EPI_QK8><<<dim3(32, 8, 4), 256, 0, stream>>>(
        hT, wbf_q, bqk, qk8, 512, 512, 512, 1024, (long)NC, 0, (long)N_ * 1024);
    // v projection -> vM8 (C,N) fp8, key-kmapped
    gemm128<EPI_V8><<<dim3(4, 32, 4), 256, 0, stream>>>(
        wbf_v, hT, bv, vM8, 512, 512, 512, 4096, 0, (long)NC, (long)NC);

    // P8 = bf8(exp(scale * q k^T)), unrounded rowsums -> denom
    exp8<<<2048, 512, 0, stream>>>(qk8, denom, P8);

    // out = x + vM8 P8^T / denom
    pv8<<<512, 256, 0, stream>>>(vM8, P8, denom, x, out);
  } else {
    // ---- fallback: round-1 path (65.5 MB ws) ----
    u16*   wbf_q = (u16*)(ws);
    u16*   wbf_k = (u16*)(ws + 524288);
    u16*   wbf_v = (u16*)(ws + 1048576);
    float* mu    = (float*)(ws + 1572864);
    float* rstd  = (float*)(ws + 1581056);
    u16*   hT    = (u16*)(ws + 1589248);
    u16*   qT    = (u16*)(ws + 18366464);
    u16*   kT    = (u16*)(ws + 35143680);
    u16*   vM    = (u16*)(ws + 51920896);

    cvt_w<<<256, 256, 0, stream>>>(wq, wbf_q);
    cvt_w<<<256, 256, 0, stream>>>(wk, wbf_k);
    cvt_w<<<256, 256, 0, stream>>>(wv, wbf_v);
    inorm_stats<<<B_ * C_, 256, 0, stream>>>(x, mu, rstd);
    norm_transpose<<<dim3(N_ / 64, C_ / 64, B_), 256, 0, stream>>>(x, mu, rstd, hT);

    for (int b = 0; b < B_; ++b) {
      const u16* hTb = hT + (size_t)b * NC;
      u16* qTb = qT + (size_t)b * NC;
      u16* kTb = kT + (size_t)b * NC;
      u16* vMb = vM + (size_t)b * NC;
      gemm_abT<<<dim3(N_ / 128, C_ / 128), 256, 0, stream>>>(hTb, wbf_q, bq, qTb, C_, 0);
      gemm_abT<<<dim3(N_ / 128, C_ / 128), 256, 0, stream>>>(hTb, wbf_k, bk, kTb, C_, 0);
      gemm_abT<<<dim3(C_ / 128, N_ / 128), 256, 0, stream>>>(wbf_v, hTb, bv, vMb, N_, 1);
    }
    attn_kernel<<<dim3(N_ / NQ, B_), 512, 0, stream>>>(qT, kT, vM, x, out);
  }
}

// Round 13
// 221.113 us; speedup vs baseline: 1.2989x; 1.0062x over previous
//
#include <hip/hip_runtime.h>
#include <hip/hip_bf16.h>
#include <cstdint>

#define B_ 4
#define C_ 512
#define N_ 4096

typedef unsigned short u16;
typedef unsigned char u8;
typedef __bf16 bf16x8 __attribute__((ext_vector_type(8)));
typedef float f32x4 __attribute__((ext_vector_type(4)));

union U16B { uint4 u; bf16x8 v; };

__device__ __forceinline__ bf16x8 ld16g(const u16* p) {
  U16B t; t.u = *(const uint4*)p; return t.v;
}

__device__ __forceinline__ u16 f2bf(float f) {
  uint32_t u = __builtin_bit_cast(uint32_t, f);
  u = (u + 0x7FFFu + ((u >> 16) & 1u)) >> 16;
  return (u16)u;
}
__device__ __forceinline__ float bf2f(u16 h) {
  uint32_t u = ((uint32_t)h) << 16;
  return __builtin_bit_cast(float, u);
}

// f32 -> fp8 e4m3fn (OCP), RNE (validated r8-r12).
__device__ __forceinline__ u8 f2fp8(float f) {
  uint32_t u = __builtin_bit_cast(uint32_t, f);
  uint32_t s = (u >> 24) & 0x80u;
  uint32_t a = u & 0x7FFFFFFFu;
  if (a >= 0x43700000u) return (u8)(s | 0x7E);
  if (a < 0x3C800000u) {
    float af = __builtin_bit_cast(float, a);
    int m = (int)(af * 512.0f + 0.5f);
    return (u8)(s | (uint32_t)m);
  }
  uint32_t r = (a + 0x7FFFFu + ((a >> 20) & 1u)) >> 20;
  return (u8)(s | (r - (120u << 3)));
}

// f32 -> bf8 e5m2 for positive values (validated r11/r12)
__device__ __forceinline__ u8 f2bf8pos(float f) {
  _Float16 h = (_Float16)f;
  u16 hb = __builtin_bit_cast(unsigned short, h);
  hb = (u16)(hb + 0x7Fu + ((hb >> 8) & 1u));
  return (u8)(hb >> 8);
}

typedef const __attribute__((address_space(1))) uint32_t* gas_p;
typedef __attribute__((address_space(3))) uint32_t* las_p;
__device__ __forceinline__ void gld16(const void* g, void* l) {
  __builtin_amdgcn_global_load_lds((gas_p)g, (las_p)l, 16, 0, 0);
}

#define SCEXP 0.06376149809794171f  /* 512^-0.5 * log2(e) */

// ---------------- K0: f32 -> bf16 weight convert (fallback path) ------------
__global__ __launch_bounds__(256) void cvt_w(const float* __restrict__ w, u16* __restrict__ o) {
  int i = blockIdx.x * 256 + threadIdx.x;
  float4 v = ((const float4*)w)[i];
  ushort4 r;
  r.x = f2bf(v.x); r.y = f2bf(v.y); r.z = f2bf(v.z); r.w = f2bf(v.w);
  ((ushort4*)o)[i] = r;
}

// ---------------- K0': f32 -> fp8 weight convert (natural, k-contig) --------
__global__ __launch_bounds__(256) void cvt_w8(const float* __restrict__ w, u8* __restrict__ o) {
  int i = blockIdx.x * 256 + threadIdx.x;         // 256 blocks x 256 thr x 4 elems
  float4 v = ((const float4*)w)[i];
  uchar4 r;
  r.x = f2fp8(v.x); r.y = f2fp8(v.y); r.z = f2fp8(v.z); r.w = f2fp8(v.w);
  ((uchar4*)o)[i] = r;
}

// ---------------- K0b: pack [bq; bk] -> 1024 f32 ----------------------------
__global__ __launch_bounds__(1024) void pack_bias(const float* __restrict__ bq,
    const float* __restrict__ bk, float* __restrict__ o) {
  int i = threadIdx.x;
  o[i] = (i < 512) ? bq[i] : bk[i - 512];
}

// ---------------- K1: instance-norm stats per (b,c) over 4096 ---------------
__global__ __launch_bounds__(256) void inorm_stats(const float* __restrict__ x,
    float* __restrict__ mu, float* __restrict__ rstd) {
  int bc = blockIdx.x;
  const float4* p = (const float4*)(x + (size_t)bc * N_);
  float s = 0.f, ss = 0.f;
  for (int i = threadIdx.x; i < N_ / 4; i += 256) {
    float4 v = p[i];
    s  += v.x + v.y + v.z + v.w;
    ss += v.x * v.x + v.y * v.y + v.z * v.z + v.w * v.w;
  }
#pragma unroll
  for (int off = 32; off > 0; off >>= 1) {
    s  += __shfl_down(s, off);
    ss += __shfl_down(ss, off);
  }
  __shared__ float as_[4], ass_[4];
  if ((threadIdx.x & 63) == 0) { as_[threadIdx.x >> 6] = s; ass_[threadIdx.x >> 6] = ss; }
  __syncthreads();
  if (threadIdx.x == 0) {
    float S  = as_[0] + as_[1] + as_[2] + as_[3];
    float SS = ass_[0] + ass_[1] + ass_[2] + ass_[3];
    float m  = S * (1.f / N_);
    float var = SS * (1.f / N_) - m * m;
    mu[bc] = m;
    rstd[bc] = rsqrtf(var + 1e-5f);
  }
}

// ---------------- K2: normalize + transpose -> hT (B,N,C) bf16 --------------
__global__ __launch_bounds__(256) void norm_transpose(const float* __restrict__ x,
    const float* __restrict__ mu, const float* __restrict__ rstd, u16* __restrict__ hT) {
  __shared__ u16 tile[64][66];
  int b = blockIdx.z, c0 = blockIdx.y * 64, n0 = blockIdx.x * 64;
  int tn = threadIdx.x & 63, t4 = threadIdx.x >> 6;
  const float* xb = x + ((size_t)b * C_ + c0) * N_ + n0;
#pragma unroll
  for (int it = 0; it < 16; ++it) {
    int c = t4 + it * 4;
    float m  = mu[b * C_ + c0 + c];
    float rs = rstd[b * C_ + c0 + c];
    tile[c][tn] = f2bf((xb[(size_t)c * N_ + tn] - m) * rs);
  }
  __syncthreads();
  u16* hTb = hT + ((size_t)b * N_ + n0) * C_ + c0;
#pragma unroll
  for (int it = 0; it < 16; ++it) {
    int n = t4 + it * 4;
    hTb[(size_t)n * C_ + tn] = tile[tn][n];
  }
}

// ---------------- K2b: hT bf16 -> h8 fp8 (natural, vectorized) --------------
__global__ __launch_bounds__(256) void cvt_h8(const u16* __restrict__ hT, u8* __restrict__ h8) {
  int i = blockIdx.x * 256 + threadIdx.x;         // 4096 blocks x 256 x 8 elems
  uint4 v = ((const uint4*)hT)[i];
  uint32_t lo =  (uint32_t)f2fp8(bf2f((u16)(v.x & 0xffff)))
              | ((uint32_t)f2fp8(bf2f((u16)(v.x >> 16))) << 8)
              | ((uint32_t)f2fp8(bf2f((u16)(v.y & 0xffff))) << 16)
              | ((uint32_t)f2fp8(bf2f((u16)(v.y >> 16))) << 24);
  uint32_t hi =  (uint32_t)f2fp8(bf2f((u16)(v.z & 0xffff)))
              | ((uint32_t)f2fp8(bf2f((u16)(v.z >> 16))) << 8)
              | ((uint32_t)f2fp8(bf2f((u16)(v.w & 0xffff))) << 16)
              | ((uint32_t)f2fp8(bf2f((u16)(v.w >> 16))) << 24);
  uint2 o; o.x = lo; o.y = hi;
  ((uint2*)h8)[i] = o;
}

// ============== proj8: fp8 projection GEMM (exp8-core, K=512) ===============
// D[m][n] = sum_k A[m][k]B[n][k] + bias; A,B fp8 natural, rows 512B.
// Correctness note: staging source-XOR and read-XOR cancel lane-wise, so any
// SHARED k-order of A and B is valid (derived r13); natural layout used.
// EPI_Q: bias[col] -> qk8 natural (granule-XOR bounce).
// EPI_V: bias[row] -> vM8 with r12 kmap (clone of exp8's P epilogue).
#define EPI_Q 0
#define EPI_V 1

template<int EPI>
__global__ __launch_bounds__(512, 3) void proj8(
    const u8* __restrict__ A, const u8* __restrict__ B,
    const float* __restrict__ aux, u8* __restrict__ Out,
    long sAz, long sBz, long sOz, int ldo)
{
  int z = blockIdx.z;
  const u8* Ab = A + (size_t)z * sAz;
  const u8* Bb = B + (size_t)z * sBz;
  u8* ob = Out + (size_t)z * sOz;
  int m0 = blockIdx.x * 128, n0 = blockIdx.y * 256;

  int t = threadIdx.x, w = t >> 6, l = t & 63;
  int wr = w >> 2, wc = w & 3;           // 2 m-halves x 4 n-quarters
  int l16 = l & 15, lg = l >> 4;

  __shared__ char smem[49152];           // dbuf 2x24KB; epilogue uses 32KB

  f32x4 acc[4][4] = {};
  int rg = ((lg ^ ((l16 >> 1) & 3)) & 3) << 4;

#define STGJ(step, lb) {                                                     \
    size_t kb = (size_t)(step) * 64;                                         \
    {                                                                        \
      int row = t >> 2, g = t & 3;                                           \
      int sg = (g ^ ((row >> 1) & 3)) << 4;                                  \
      gld16((const char*)Ab + (size_t)(m0 + row) * 512 + kb + sg,            \
            (lb) + (size_t)t * 16);                                          \
    }                                                                        \
    _Pragma("unroll")                                                        \
    for (int i = 0; i < 2; ++i) {                                            \
      int s2 = i * 512 + t;                                                  \
      int row = s2 >> 2, g = s2 & 3;                                         \
      int sg = (g ^ ((row >> 1) & 3)) << 4;                                  \
      gld16((const char*)Bb + (size_t)(n0 + row) * 512 + kb + sg,            \
            (lb) + 8192 + (size_t)s2 * 16);                                  \
    }                                                                        \
  }

#define COMPJ(lb) {                                                          \
    const char* Al = (lb);                                                   \
    const char* Bl = (lb) + 8192;                                            \
    uint4 af[4], bf[4];                                                      \
    _Pragma("unroll")                                                        \
    for (int mf = 0; mf < 4; ++mf)                                           \
      af[mf] = *(const uint4*)(Al + (wr * 64 + mf * 16 + l16) * 64 + rg);    \
    _Pragma("unroll")                                                        \
    for (int nf = 0; nf < 4; ++nf)                                           \
      bf[nf] = *(const uint4*)(Bl + (wc * 64 + nf * 16 + l16) * 64 + rg);    \
    _Pragma("unroll")                                                        \
    for (int kk = 0; kk < 2; ++kk) {                                         \
      _Pragma("unroll")                                                      \
      for (int mf = 0; mf < 4; ++mf) {                                       \
        long long a8 = ((long long)(kk ? af[mf].w : af[mf].y) << 32) |       \
                       (unsigned int)(kk ? af[mf].z : af[mf].x);             \
        _Pragma("unroll")                                                    \
        for (int nf = 0; nf < 4; ++nf) {                                     \
          long long b8 = ((long long)(kk ? bf[nf].w : bf[nf].y) << 32) |     \
                         (unsigned int)(kk ? bf[nf].z : bf[nf].x);           \
          acc[mf][nf] = __builtin_amdgcn_mfma_f32_16x16x32_fp8_fp8(          \
              a8, b8, acc[mf][nf], 0, 0, 0);                                 \
        }                                                                    \
      }                                                                      \
    }                                                                        \
  }

  char* buf0 = smem;
  char* buf1 = smem + 24576;

  STGJ(0, buf0);
#pragma unroll
  for (int s = 0; s < 8; ++s) {
    char* cb = (s & 1) ? buf1 : buf0;
    char* nb = (s & 1) ? buf0 : buf1;
    if (s < 7) {
      STGJ(s + 1, nb);
      asm volatile("s_waitcnt vmcnt(3)" ::: "memory");
    } else {
      asm volatile("s_waitcnt vmcnt(0)" ::: "memory");
    }
    __builtin_amdgcn_s_barrier();
    __builtin_amdgcn_sched_barrier(0);
    COMPJ(cb);
    __builtin_amdgcn_sched_barrier(0);
    __builtin_amdgcn_s_barrier();
  }
#undef STGJ
#undef COMPJ

  if constexpr (EPI == EPI_Q) {
    float bc[4];
#pragma unroll
    for (int nf = 0; nf < 4; ++nf) bc[nf] = aux[n0 + wc * 64 + nf * 16 + l16];
#pragma unroll
    for (int mf = 0; mf < 4; ++mf) {
#pragma unroll
      for (int r = 0; r < 4; ++r) {
        int row = wr * 64 + mf * 16 + lg * 4 + r;    // 0..127
        int gx = ((row >> 2) & 3) << 4;
#pragma unroll
        for (int nf = 0; nf < 4; ++nf) {
          int cl = wc * 64 + nf * 16 + l16;          // 0..255
          smem[row * 256 + (cl ^ gx)] = (char)f2fp8(acc[mf][nf][r] + bc[nf]);
        }
      }
    }
    __syncthreads();
#pragma unroll
    for (int it = 0; it < 4; ++it) {
      int idx = it * 512 + t;
      int row = idx >> 4, seg = idx & 15;
      int gx = ((row >> 2) & 3) << 4;
      uint4 v = *(const uint4*)(smem + row * 256 + ((seg * 16) ^ gx));
      *(uint4*)(ob + (size_t)(m0 + row) * ldo + n0 + seg * 16) = v;
    }
  } else {  // EPI_V: kmap-packed u32 per 64-key group (r12 exp8-P pattern)
#pragma unroll
    for (int mf = 0; mf < 4; ++mf) {
#pragma unroll
      for (int r = 0; r < 4; ++r) {
        int row = wr * 64 + mf * 16 + lg * 4 + r;    // 0..127; (row>>2)&3 == lg
        float brow = aux[m0 + row];
        uint32_t pk = 0;
#pragma unroll
        for (int nf = 0; nf < 4; ++nf)
          pk |= (uint32_t)f2fp8(acc[mf][nf][r] + brow) << (8 * nf);
        int blk = (wc ^ lg) << 6;
        *(uint32_t*)(smem + row * 256 + blk + l16 * 4) = pk;
      }
    }
    __syncthreads();
#pragma unroll
    for (int it = 0; it < 4; ++it) {
      int idx = it * 512 + t;
      int row = idx >> 4, seg = idx & 15;
      int blk = ((seg >> 2) ^ ((row >> 2) & 3)) << 6;
      uint4 v = *(const uint4*)(smem + row * 256 + blk + (seg & 3) * 16);
      *(uint4*)(ob + (size_t)(m0 + row) * ldo + n0 + seg * 16) = v;
    }
  }
}

// ============== exp8: 128x256 tile, fp8, BK=64, dbuf + vmcnt(3) =============
// (byte-identical to r12) P out = bf8 e5m2, kmap pos=(l16<<2)|nf per 64-key
// group (matches EPI_V's vM8 kmap -> pv8 contracts by position).
__global__ __launch_bounds__(512, 3) void exp8(
    const u8* __restrict__ qk8, float* __restrict__ dsumAll, u8* __restrict__ Pall)
{
  int fid = blockIdx.x;                  // 2048 blocks
  int rid = (fid & 7) * 256 + (fid >> 3);
  int z = rid >> 9;
  int r9 = rid & 511;
  int c2 = r9 >> 8;
  int r8 = r9 & 255;
  int sm = r8 >> 6, w6s = r8 & 63;
  int m0 = (c2 * 16 + (sm >> 1) * 8 + (w6s >> 3)) * 128;
  int n0 = ((sm & 1) * 8 + (w6s & 7)) * 256;

  const u8* Ab = qk8 + (size_t)z * ((size_t)N_ * 1024);        // q half
  const u8* Bb = Ab + 512;                                     // k half
  float* dsum = dsumAll + (size_t)z * N_;
  u8* Pp = Pall + (size_t)z * (size_t)N_ * N_;

  int t = threadIdx.x, w = t >> 6, l = t & 63;
  int wr = w >> 2, wc = w & 3;
  int l16 = l & 15, lg = l >> 4;

  __shared__ char smem[49152];

  f32x4 acc[4][4] = {};
  int rg = ((lg ^ ((l16 >> 1) & 3)) & 3) << 4;

#define STG8(step, lb) {                                                     \
    size_t kb = (size_t)(step) * 64;                                         \
    {                                                                        \
      int row = t >> 2, g = t & 3;                                           \
      int sg = (g ^ ((row >> 1) & 3)) << 4;                                  \
      gld16((const char*)Ab + (size_t)(m0 + row) * 1024 + kb + sg,           \
            (lb) + (size_t)t * 16);                                          \
    }                                                                        \
    _Pragma("unroll")                                                        \
    for (int i = 0; i < 2; ++i) {                                            \
      int s2 = i * 512 + t;                                                  \
      int row = s2 >> 2, g = s2 & 3;                                         \
      int sg = (g ^ ((row >> 1) & 3)) << 4;                                  \
      gld16((const char*)Bb + (size_t)(n0 + row) * 1024 + kb + sg,           \
            (lb) + 8192 + (size_t)s2 * 16);                                  \
    }                                                                        \
  }

#define COMP8(lb) {                                                          \
    const char* Al = (lb);                                                   \
    const char* Bl = (lb) + 8192;                                            \
    uint4 af[4], bf[4];                                                      \
    _Pragma("unroll")                                                        \
    for (int mf = 0; mf < 4; ++mf)                                           \
      af[mf] = *(const uint4*)(Al + (wr * 64 + mf * 16 + l16) * 64 + rg);    \
    _Pragma("unroll")                                                        \
    for (int nf = 0; nf < 4; ++nf)                                           \
      bf[nf] = *(const uint4*)(Bl + (wc * 64 + nf * 16 + l16) * 64 + rg);    \
    _Pragma("unroll")                                                        \
    for (int kk = 0; kk < 2; ++kk) {                                         \
      _Pragma("unroll")                                                      \
      for (int mf = 0; mf < 4; ++mf) {                                       \
        long long a8 = ((long long)(kk ? af[mf].w : af[mf].y) << 32) |       \
                       (unsigned int)(kk ? af[mf].z : af[mf].x);             \
        _Pragma("unroll")                                                    \
        for (int nf = 0; nf < 4; ++nf) {                                     \
          long long b8 = ((long long)(kk ? bf[nf].w : bf[nf].y) << 32) |     \
                         (unsigned int)(kk ? bf[nf].z : bf[nf].x);           \
          acc[mf][nf] = __builtin_amdgcn_mfma_f32_16x16x32_fp8_fp8(          \
              a8, b8, acc[mf][nf], 0, 0, 0);                                 \
        }                                                                    \
      }                                                                      \
    }                                                                        \
  }

  char* buf0 = smem;
  char* buf1 = smem + 24576;

  STG8(0, buf0);
#pragma unroll
  for (int s = 0; s < 8; ++s) {
    char* cb = (s & 1) ? buf1 : buf0;
    char* nb = (s & 1) ? buf0 : buf1;
    if (s < 7) {
      STG8(s + 1, nb);
      asm volatile("s_waitcnt vmcnt(3)" ::: "memory");
    } else {
      asm volatile("s_waitcnt vmcnt(0)" ::: "memory");
    }
    __builtin_amdgcn_s_barrier();
    __builtin_amdgcn_sched_barrier(0);
    COMP8(cb);
    __builtin_amdgcn_sched_barrier(0);
    __builtin_amdgcn_s_barrier();
  }
#undef STG8
#undef COMP8

#pragma unroll
  for (int mf = 0; mf < 4; ++mf) {
#pragma unroll
    for (int r = 0; r < 4; ++r) {
      int row = wr * 64 + mf * 16 + lg * 4 + r;
      float rs = 0.f;
      uint32_t pk = 0;
#pragma unroll
      for (int nf = 0; nf < 4; ++nf) {
        float p = __builtin_amdgcn_exp2f(acc[mf][nf][r] * SCEXP);
        rs += p;
        pk |= (uint32_t)f2bf8pos(p) << (8 * nf);
      }
      int blk = (wc ^ lg) << 6;
      *(uint32_t*)(smem + row * 256 + blk + l16 * 4) = pk;
      rs += __shfl_xor(rs, 1); rs += __shfl_xor(rs, 2);
      rs += __shfl_xor(rs, 4); rs += __shfl_xor(rs, 8);
      if (l16 == 0) atomicAdd(&dsum[m0 + row], rs);
    }
  }
  __syncthreads();
#pragma unroll
  for (int it = 0; it < 4; ++it) {
    int idx = it * 512 + t;
    int row = idx >> 4, seg = idx & 15;
    int blk = ((seg >> 2) ^ ((row >> 2) & 3)) << 6;
    *(uint4*)(Pp + ((size_t)(m0 + row) * N_ + n0 + seg * 16)) =
        *(const uint4*)(smem + row * 256 + blk + (seg & 3) * 16);
  }
}

// ============== pv8: out = x + vM8 P8^T / denom (e4m3 x e5m2) ===============
// (byte-identical to r12)
__global__ __launch_bounds__(256, 4) void pv8(
    const u8* __restrict__ vM8, const u8* __restrict__ P8,
    const float* __restrict__ denom, const float* __restrict__ x,
    float* __restrict__ out)
{
  int fid = blockIdx.x;                 // 512 blocks
  int rid = (fid & 7) * 64 + (fid >> 3);
  int z = rid >> 7;
  int r7 = rid & 127;
  int n0 = (r7 >> 2) * 128;
  int m0 = (r7 & 3) * 128;

  const u8* Ab = vM8 + (size_t)z * ((size_t)C_ * N_);
  const u8* Bb = P8 + (size_t)z * ((size_t)N_ * N_);
  const float* db = denom + (size_t)z * N_;
  const float* xb = x + (size_t)z * ((size_t)C_ * N_);
  float* ob = out + (size_t)z * ((size_t)C_ * N_);

  int t = threadIdx.x, w = t >> 6, l = t & 63;
  int wr = w >> 1, wc = w & 1;
  int l16 = l & 15, lg = l >> 4;

  __shared__ char smem[32768];

  f32x4 acc[4][4] = {};
  int rg = ((lg ^ ((l16 >> 1) & 3)) & 3) << 4;

#define STGP(step, lb) {                                                     \
    size_t kb = (size_t)(step) * 64;                                         \
    _Pragma("unroll")                                                        \
    for (int i = 0; i < 2; ++i) {                                            \
      int s2 = i * 256 + t;                                                  \
      int row = s2 >> 2, g = s2 & 3;                                         \
      int sg = (g ^ ((row >> 1) & 3)) << 4;                                  \
      gld16((const char*)Ab + (size_t)(m0 + row) * N_ + kb + sg,             \
            (lb) + (size_t)s2 * 16);                                         \
      gld16((const char*)Bb + (size_t)(n0 + row) * N_ + kb + sg,             \
            (lb) + 8192 + (size_t)s2 * 16);                                  \
    }                                                                        \
  }

#define COMPP(lb) {                                                          \
    const char* Al = (lb);                                                   \
    const char* Bl = (lb) + 8192;                                            \
    uint4 af[4], bf[4];                                                      \
    _Pragma("unroll")                                                        \
    for (int mf = 0; mf < 4; ++mf)                                           \
      af[mf] = *(const uint4*)(Al + (wr * 64 + mf * 16 + l16) * 64 + rg);    \
    _Pragma("unroll")                                                        \
    for (int nf = 0; nf < 4; ++nf)                                           \
      bf[nf] = *(const uint4*)(Bl + (wc * 64 + nf * 16 + l16) * 64 + rg);    \
    _Pragma("unroll")                                                        \
    for (int kk = 0; kk < 2; ++kk) {                                         \
      _Pragma("unroll")                                                      \
      for (int mf = 0; mf < 4; ++mf) {                                       \
        long long a8 = ((long long)(kk ? af[mf].w : af[mf].y) << 32) |       \
                       (unsigned int)(kk ? af[mf].z : af[mf].x);             \
        _Pragma("unroll")                                                    \
        for (int nf = 0; nf < 4; ++nf) {                                     \
          long long b8 = ((long long)(kk ? bf[nf].w : bf[nf].y) << 32) |     \
                         (unsigned int)(kk ? bf[nf].z : bf[nf].x);           \
          acc[mf][nf] = __builtin_amdgcn_mfma_f32_16x16x32_fp8_bf8(          \
              a8, b8, acc[mf][nf], 0, 0, 0);                                 \
        }                                                                    \
      }                                                                      \
    }                                                                        \
  }

  char* buf0 = smem;
  char* buf1 = smem + 16384;

  STGP(0, buf0);
#pragma unroll 2
  for (int s = 0; s < 64; ++s) {
    char* cb = (s & 1) ? buf1 : buf0;
    char* nb = (s & 1) ? buf0 : buf1;
    if (s < 63) {
      STGP(s + 1, nb);
      asm volatile("s_waitcnt vmcnt(4)" ::: "memory");
    } else {
      asm volatile("s_waitcnt vmcnt(0)" ::: "memory");
    }
    __builtin_amdgcn_s_barrier();
    __builtin_amdgcn_sched_barrier(0);
    COMPP(cb);
    __builtin_amdgcn_sched_barrier(0);
    __builtin_amdgcn_s_barrier();
  }
#undef STGP
#undef COMPP

  float rd[4];
#pragma unroll
  for (int nf = 0; nf < 4; ++nf)
    rd[nf] = 1.0f / db[n0 + wc * 64 + nf * 16 + l16];
#pragma unroll
  for (int mf = 0; mf < 4; ++mf) {
#pragma unroll
    for (int r = 0; r < 4; ++r) {
      int row = m0 + wr * 64 + mf * 16 + lg * 4 + r;
#pragma unroll
      for (int nf = 0; nf < 4; ++nf) {
        int col = n0 + wc * 64 + nf * 16 + l16;
        size_t o = (size_t)row * N_ + col;
        ob[o] = xb[o] + acc[mf][nf][r] * rd[nf];
      }
    }
  }
}

// ================== round-1 fallback path (tiny ws) =========================
__global__ __launch_bounds__(256) void gemm_abT(
    const u16* __restrict__ A, const u16* __restrict__ Bm,
    const float* __restrict__ bias, u16* __restrict__ out,
    int ldo, int bias_is_row)
{
  int w = threadIdx.x >> 6, l = threadIdx.x & 63;
  int l16 = l & 15, lg = l >> 4;
  int m0 = blockIdx.x * 128 + (w >> 1) * 64;
  int n0 = blockIdx.y * 128 + (w & 1) * 64;
  f32x4 acc[4][4] = {};
  const u16* Ab = A  + (size_t)(m0 + l16) * 512 + lg * 8;
  const u16* Bb = Bm + (size_t)(n0 + l16) * 512 + lg * 8;
  for (int kc = 0; kc < 512; kc += 32) {
    bf16x8 af[4], bf[4];
#pragma unroll
    for (int i = 0; i < 4; ++i) af[i] = ld16g(Ab + (size_t)(i * 16) * 512 + kc);
#pragma unroll
    for (int j = 0; j < 4; ++j) bf[j] = ld16g(Bb + (size_t)(j * 16) * 512 + kc);
#pragma unroll
    for (int i = 0; i < 4; ++i)
#pragma unroll
      for (int j = 0; j < 4; ++j)
        acc[i][j] = __builtin_amdgcn_mfma_f32_16x16x32_bf16(af[i], bf[j], acc[i][j], 0, 0, 0);
  }
#pragma unroll
  for (int i = 0; i < 4; ++i) {
#pragma unroll
    for (int j = 0; j < 4; ++j) {
      int col = n0 + j * 16 + l16;
#pragma unroll
      for (int r = 0; r < 4; ++r) {
        int row = m0 + i * 16 + lg * 4 + r;
        float v = acc[i][j][r] + (bias_is_row ? bias[row] : bias[col]);
        out[(size_t)row * ldo + col] = f2bf(v);
      }
    }
  }
}

#define NQ 32
#define NKB 64
__global__ __launch_bounds__(512) void attn_kernel(
    const u16* __restrict__ qT, const u16* __restrict__ kT, const u16* __restrict__ vM,
    const float* __restrict__ x, float* __restrict__ out)
{
  int b = blockIdx.y;
  int nq0 = blockIdx.x * NQ;
  const u16* qTb = qT + (size_t)b * N_ * C_;
  const u16* kTb = kT + (size_t)b * N_ * C_;
  const u16* vb  = vM + (size_t)b * C_ * N_;
  const float* xb = x + (size_t)b * C_ * N_;
  float* ob = out + (size_t)b * C_ * N_;

  int tid = threadIdx.x;
  int w = tid >> 6, l = tid & 63, l16 = l & 15, lg = l >> 4;
  int nqf = w & 1, nkf = w >> 1;
  int c0 = w * 64;

  __shared__ u16 qlds[32][520];
  __shared__ u16 Plds[32][72];
  __shared__ float dpart[32][16];
  __shared__ float dfin[32];

  for (int idx = tid; idx < 32 * 64; idx += 512) {
    int row = idx >> 6, cg = idx & 63;
    *(uint4*)&qlds[row][cg * 8] = *(const uint4*)(qTb + (size_t)(nq0 + row) * C_ + cg * 8);
  }
  __syncthreads();

  f32x4 acc[2][4] = {};
  float dreg = 0.f;
  int drow = tid >> 4, dcol = (tid & 15) * 4;

  for (int nk0 = 0; nk0 < N_; nk0 += NKB) {
    f32x4 s = {0.f, 0.f, 0.f, 0.f};
    const u16* krow = kTb + (size_t)(nk0 + nkf * 16 + l16) * C_ + lg * 8;
#pragma unroll 4
    for (int kc = 0; kc < 16; ++kc) {
      U16B tq; tq.u = *(const uint4*)&qlds[nqf * 16 + l16][kc * 32 + lg * 8];
      bf16x8 kf = ld16g(krow + kc * 32);
      s = __builtin_amdgcn_mfma_f32_16x16x32_bf16(tq.v, kf, s, 0, 0, 0);
    }
    __syncthreads();
#pragma unroll
    for (int r = 0; r < 4; ++r) {
      float p = __builtin_amdgcn_exp2f(s[r] * SCEXP);
      Plds[nqf * 16 + lg * 4 + r][nkf * 16 + l16] = f2bf(p);
    }
    __syncthreads();
#pragma unroll
    for (int r = 0; r < 4; ++r) dreg += bf2f(Plds[drow][dcol + r]);
#pragma unroll
    for (int kk = 0; kk < 2; ++kk) {
      bf16x8 pf[2];
#pragma unroll
      for (int i = 0; i < 2; ++i) {
        U16B t2; t2.u = *(const uint4*)&Plds[i * 16 + l16][kk * 32 + lg * 8];
        pf[i] = t2.v;
      }
#pragma unroll
      for (int j = 0; j < 4; ++j) {
        bf16x8 vf = ld16g(vb + (size_t)(c0 + j * 16 + l16) * N_ + nk0 + kk * 32 + lg * 8);
#pragma unroll
        for (int i = 0; i < 2; ++i)
          acc[i][j] = __builtin_amdgcn_mfma_f32_16x16x32_bf16(pf[i], vf, acc[i][j], 0, 0, 0);
      }
    }
  }

  dpart[drow][tid & 15] = dreg;
  __syncthreads();
  if (tid < 32) {
    float s2 = 0.f;
#pragma unroll
    for (int g = 0; g < 16; ++g) s2 += dpart[tid][g];
    dfin[tid] = s2;
  }
  __syncthreads();

#pragma unroll
  for (int i = 0; i < 2; ++i) {
    float dinv[4];
#pragma unroll
    for (int r = 0; r < 4; ++r) dinv[r] = 1.f / dfin[i * 16 + lg * 4 + r];
    int nbase = nq0 + i * 16 + lg * 4;
#pragma unroll
    for (int j = 0; j < 4; ++j) {
      int c = c0 + j * 16 + l16;
      float4 xv = *(const float4*)(xb + (size_t)c * N_ + nbase);
      float4 o;
      o.x = xv.x + acc[i][j][0] * dinv[0];
      o.y = xv.y + acc[i][j][1] * dinv[1];
      o.z = xv.z + acc[i][j][2] * dinv[2];
      o.w = xv.w + acc[i][j][3] * dinv[3];
      *(float4*)(ob + (size_t)c * N_ + nbase) = o;
    }
  }
}

extern "C" void kernel_launch(void* const* d_in, const int* in_sizes, int n_in,
                              void* d_out, int out_size, void* d_ws, size_t ws_size,
                              hipStream_t stream) {
  (void)in_sizes; (void)n_in; (void)out_size;
  const float* x  = (const float*)d_in[0];
  const float* wq = (const float*)d_in[1];
  const float* bq = (const float*)d_in[2];
  const float* wk = (const float*)d_in[3];
  const float* bk = (const float*)d_in[4];
  const float* wv = (const float*)d_in[5];
  const float* bv = (const float*)d_in[6];
  float* out = (float*)d_out;
  char* ws = (char*)d_ws;

  const size_t NC = (size_t)N_ * C_;        // 2097152 elems
  const size_t NEED = 118312960;

  if (ws_size >= NEED) {
    u8*    wqk8  = (u8*)(ws);               // 512 KB: wq8 | wk8 (rows 0..1023)
    u8*    wv8   = (u8*)(ws + 524288);      // 256 KB
    float* bqk   = (float*)(ws + 786432);
    float* mu    = (float*)(ws + 790528);
    float* rstd  = (float*)(ws + 798720);
    u16*   hT    = (u16*)(ws + 806912);     // 16.8 MB (B,N,C) bf16
    u8*    h8    = (u8*)(ws + 17584128);    //  8.4 MB (B,N,C) fp8 natural
    u8*    qk8   = (u8*)(ws + 25972736);    // 16.8 MB (B,N,1024) fp8 natural
    u8*    vM8   = (u8*)(ws + 42749952);    //  8.4 MB (B,C,N) fp8 key-kmap
    float* denom = (float*)(ws + 51138560); // 64 KB
    u8*    P8    = (u8*)(ws + 51204096);    // 67.1 MB (B,N,N) bf8 key-kmap

    cvt_w8<<<256, 256, 0, stream>>>(wq, wqk8);
    cvt_w8<<<256, 256, 0, stream>>>(wk, wqk8 + 262144);
    cvt_w8<<<256, 256, 0, stream>>>(wv, wv8);
    pack_bias<<<1, 1024, 0, stream>>>(bq, bk, bqk);
    inorm_stats<<<B_ * C_, 256, 0, stream>>>(x, mu, rstd);
    norm_transpose<<<dim3(N_ / 64, C_ / 64, B_), 256, 0, stream>>>(x, mu, rstd, hT);
    cvt_h8<<<4096, 256, 0, stream>>>(hT, h8);
    hipMemsetAsync(denom, 0, 4 * N_ * sizeof(float), stream);

    // q+k projection (fp8): qk8[n][o] = sum_c h8[n][c] wqk8[o][c] + bqk[o]
    proj8<EPI_Q><<<dim3(32, 4, 4), 512, 0, stream>>>(
        h8, wqk8, bqk, qk8, (long)NC, 0, (long)N_ * 1024, 1024);
    // v projection (fp8): vM8[c][n] = sum_ch wv8[c][ch] h8[n][ch] + bv[c]
    proj8<EPI_V><<<dim3(4, 16, 4), 512, 0, stream>>>(
        wv8, h8, bv, vM8, 0, (long)NC, (long)NC, 4096);

    // P8 = bf8(exp(scale * q k^T)), unrounded rowsums -> denom
    exp8<<<2048, 512, 0, stream>>>(qk8, denom, P8);

    // out = x + vM8 P8^T / denom
    pv8<<<512, 256, 0, stream>>>(vM8, P8, denom, x, out);
  } else {
    // ---- fallback: round-1 path (65.5 MB ws) ----
    u16*   wbf_q = (u16*)(ws);
    u16*   wbf_k = (u16*)(ws + 524288);
    u16*   wbf_v = (u16*)(ws + 1048576);
    float* mu    = (float*)(ws + 1572864);
    float* rstd  = (float*)(ws + 1581056);
    u16*   hT    = (u16*)(ws + 1589248);
    u16*   qT    = (u16*)(ws + 18366464);
    u16*   kT    = (u16*)(ws + 35143680);
    u16*   vM    = (u16*)(ws + 51920896);

    cvt_w<<<256, 256, 0, stream>>>(wq, wbf_q);
    cvt_w<<<256, 256, 0, stream>>>(wk, wbf_k);
    cvt_w<<<256, 256, 0, stream>>>(wv, wbf_v);
    inorm_stats<<<B_ * C_, 256, 0, stream>>>(x, mu, rstd);
    norm_transpose<<<dim3(N_ / 64, C_ / 64, B_), 256, 0, stream>>>(x, mu, rstd, hT);

    for (int b = 0; b < B_; ++b) {
      const u16* hTb = hT + (size_t)b * NC;
      u16* qTb = qT + (size_t)b * NC;
      u16* kTb = kT + (size_t)b * NC;
      u16* vMb = vM + (size_t)b * NC;
      gemm_abT<<<dim3(N_ / 128, C_ / 128), 256, 0, stream>>>(hTb, wbf_q, bq, qTb, C_, 0);
      gemm_abT<<<dim3(N_ / 128, C_ / 128), 256, 0, stream>>>(hTb, wbf_k, bk, kTb, C_, 0);
      gemm_abT<<<dim3(C_ / 128, N_ / 128), 256, 0, stream>>>(wbf_v, hTb, bv, vMb, N_, 1);
    }
    attn_kernel<<<dim3(N_ / NQ, B_), 512, 0, stream>>>(qT, kT, vM, x, out);
  }
}

// Round 14
// 219.594 us; speedup vs baseline: 1.3079x; 1.0069x over previous
//
#include <hip/hip_runtime.h>
#include <hip/hip_bf16.h>
#include <cstdint>

#define B_ 4
#define C_ 512
#define N_ 4096

typedef unsigned short u16;
typedef unsigned char u8;
typedef __bf16 bf16x8 __attribute__((ext_vector_type(8)));
typedef float f32x4 __attribute__((ext_vector_type(4)));

union U16B { uint4 u; bf16x8 v; };

__device__ __forceinline__ bf16x8 ld16g(const u16* p) {
  U16B t; t.u = *(const uint4*)p; return t.v;
}

__device__ __forceinline__ u16 f2bf(float f) {
  uint32_t u = __builtin_bit_cast(uint32_t, f);
  u = (u + 0x7FFFu + ((u >> 16) & 1u)) >> 16;
  return (u16)u;
}
__device__ __forceinline__ float bf2f(u16 h) {
  uint32_t u = ((uint32_t)h) << 16;
  return __builtin_bit_cast(float, u);
}

// f32 -> fp8 e4m3fn (OCP), RNE (validated r8-r13).
__device__ __forceinline__ u8 f2fp8(float f) {
  uint32_t u = __builtin_bit_cast(uint32_t, f);
  uint32_t s = (u >> 24) & 0x80u;
  uint32_t a = u & 0x7FFFFFFFu;
  if (a >= 0x43700000u) return (u8)(s | 0x7E);
  if (a < 0x3C800000u) {
    float af = __builtin_bit_cast(float, a);
    int m = (int)(af * 512.0f + 0.5f);
    return (u8)(s | (uint32_t)m);
  }
  uint32_t r = (a + 0x7FFFFu + ((a >> 20) & 1u)) >> 20;
  return (u8)(s | (r - (120u << 3)));
}

// f32 -> bf8 e5m2 for positive values (validated r11-r13)
__device__ __forceinline__ u8 f2bf8pos(float f) {
  _Float16 h = (_Float16)f;
  u16 hb = __builtin_bit_cast(unsigned short, h);
  hb = (u16)(hb + 0x7Fu + ((hb >> 8) & 1u));
  return (u8)(hb >> 8);
}

typedef const __attribute__((address_space(1))) uint32_t* gas_p;
typedef __attribute__((address_space(3))) uint32_t* las_p;
__device__ __forceinline__ void gld16(const void* g, void* l) {
  __builtin_amdgcn_global_load_lds((gas_p)g, (las_p)l, 16, 0, 0);
}

#define SCEXP 0.06376149809794171f  /* 512^-0.5 * log2(e) */

// ---------------- K0: f32 -> bf16 weight convert (fallback path) ------------
__global__ __launch_bounds__(256) void cvt_w(const float* __restrict__ w, u16* __restrict__ o) {
  int i = blockIdx.x * 256 + threadIdx.x;
  float4 v = ((const float4*)w)[i];
  ushort4 r;
  r.x = f2bf(v.x); r.y = f2bf(v.y); r.z = f2bf(v.z); r.w = f2bf(v.w);
  ((ushort4*)o)[i] = r;
}

// ---------------- prep_wb: all weights -> fp8 + bias pack in ONE launch -----
__global__ __launch_bounds__(256) void prep_wb(
    const float* __restrict__ wq, const float* __restrict__ wk,
    const float* __restrict__ wv, const float* __restrict__ bq,
    const float* __restrict__ bk, u8* __restrict__ wqk8,
    u8* __restrict__ wv8, float* __restrict__ bqk)
{
  int blk = blockIdx.x, t = threadIdx.x;
  if (blk < 768) {
    const float* src = blk < 256 ? wq : (blk < 512 ? wk : wv);
    u8* dst = blk < 256 ? wqk8 : (blk < 512 ? wqk8 + 262144 : wv8);
    int i = (blk & 255) * 256 + t;
    float4 v = ((const float4*)src)[i];
    uchar4 r;
    r.x = f2fp8(v.x); r.y = f2fp8(v.y); r.z = f2fp8(v.z); r.w = f2fp8(v.w);
    ((uchar4*)dst)[i] = r;
  } else {
#pragma unroll
    for (int j = 0; j < 4; ++j) {
      int i = j * 256 + t;
      bqk[i] = (i < 512) ? bq[i] : bk[i - 512];
    }
  }
}

// ---------------- K1: instance-norm stats per (b,c) over 4096 ---------------
__global__ __launch_bounds__(256) void inorm_stats(const float* __restrict__ x,
    float* __restrict__ mu, float* __restrict__ rstd) {
  int bc = blockIdx.x;
  const float4* p = (const float4*)(x + (size_t)bc * N_);
  float s = 0.f, ss = 0.f;
  for (int i = threadIdx.x; i < N_ / 4; i += 256) {
    float4 v = p[i];
    s  += v.x + v.y + v.z + v.w;
    ss += v.x * v.x + v.y * v.y + v.z * v.z + v.w * v.w;
  }
#pragma unroll
  for (int off = 32; off > 0; off >>= 1) {
    s  += __shfl_down(s, off);
    ss += __shfl_down(ss, off);
  }
  __shared__ float as_[4], ass_[4];
  if ((threadIdx.x & 63) == 0) { as_[threadIdx.x >> 6] = s; ass_[threadIdx.x >> 6] = ss; }
  __syncthreads();
  if (threadIdx.x == 0) {
    float S  = as_[0] + as_[1] + as_[2] + as_[3];
    float SS = ass_[0] + ass_[1] + ass_[2] + ass_[3];
    float m  = S * (1.f / N_);
    float var = SS * (1.f / N_) - m * m;
    mu[bc] = m;
    rstd[bc] = rsqrtf(var + 1e-5f);
  }
}

// ---------------- norm_h8: normalize + transpose -> h8 fp8 DIRECT -----------
// Tile 128c x 64n; bf16 LDS tile [128][66] (all phases <=2-way banks = free).
// Writes h8[n][c0..c0+128) = full 128B lines (2 waves/row).
__global__ __launch_bounds__(256) void norm_h8(const float* __restrict__ x,
    const float* __restrict__ mu, const float* __restrict__ rstd, u8* __restrict__ h8) {
  __shared__ u16 tile[128][66];
  int b = blockIdx.z, c0 = blockIdx.y * 128, n0 = blockIdx.x * 64;
  int t = threadIdx.x;
  const float* xb = x + ((size_t)b * C_ + c0) * N_ + n0;
#pragma unroll
  for (int it = 0; it < 32; ++it) {
    int idx = it * 256 + t;
    int row = idx >> 6, n = idx & 63;
    float m  = mu[b * C_ + c0 + row];
    float rs = rstd[b * C_ + c0 + row];
    tile[row][n] = f2bf((xb[(size_t)row * N_ + n] - m) * rs);
  }
  __syncthreads();
  u8* ob = h8 + ((size_t)b * N_ + n0) * C_ + c0;
#pragma unroll
  for (int it = 0; it < 32; ++it) {
    int idx = it * 256 + t;
    int n = idx >> 7, c = idx & 127;
    ob[(size_t)n * C_ + c] = f2fp8(bf2f(tile[c][n]));
  }
}

// ---------------- norm_transpose (fallback path only) -----------------------
__global__ __launch_bounds__(256) void norm_transpose(const float* __restrict__ x,
    const float* __restrict__ mu, const float* __restrict__ rstd, u16* __restrict__ hT) {
  __shared__ u16 tile[64][66];
  int b = blockIdx.z, c0 = blockIdx.y * 64, n0 = blockIdx.x * 64;
  int tn = threadIdx.x & 63, t4 = threadIdx.x >> 6;
  const float* xb = x + ((size_t)b * C_ + c0) * N_ + n0;
#pragma unroll
  for (int it = 0; it < 16; ++it) {
    int c = t4 + it * 4;
    float m  = mu[b * C_ + c0 + c];
    float rs = rstd[b * C_ + c0 + c];
    tile[c][tn] = f2bf((xb[(size_t)c * N_ + tn] - m) * rs);
  }
  __syncthreads();
  u16* hTb = hT + ((size_t)b * N_ + n0) * C_ + c0;
#pragma unroll
  for (int it = 0; it < 16; ++it) {
    int n = t4 + it * 4;
    hTb[(size_t)n * C_ + tn] = tile[tn][n];
  }
}

// ============== proj8: fp8 projection GEMM (exp8-core, K=512) ===============
// (byte-identical to r13)
#define EPI_Q 0
#define EPI_V 1

template<int EPI>
__global__ __launch_bounds__(512, 3) void proj8(
    const u8* __restrict__ A, const u8* __restrict__ B,
    const float* __restrict__ aux, u8* __restrict__ Out,
    long sAz, long sBz, long sOz, int ldo)
{
  int z = blockIdx.z;
  const u8* Ab = A + (size_t)z * sAz;
  const u8* Bb = B + (size_t)z * sBz;
  u8* ob = Out + (size_t)z * sOz;
  int m0 = blockIdx.x * 128, n0 = blockIdx.y * 256;

  int t = threadIdx.x, w = t >> 6, l = t & 63;
  int wr = w >> 2, wc = w & 3;
  int l16 = l & 15, lg = l >> 4;

  __shared__ char smem[49152];

  f32x4 acc[4][4] = {};
  int rg = ((lg ^ ((l16 >> 1) & 3)) & 3) << 4;

#define STGJ(step, lb) {                                                     \
    size_t kb = (size_t)(step) * 64;                                         \
    {                                                                        \
      int row = t >> 2, g = t & 3;                                           \
      int sg = (g ^ ((row >> 1) & 3)) << 4;                                  \
      gld16((const char*)Ab + (size_t)(m0 + row) * 512 + kb + sg,            \
            (lb) + (size_t)t * 16);                                          \
    }                                                                        \
    _Pragma("unroll")                                                        \
    for (int i = 0; i < 2; ++i) {                                            \
      int s2 = i * 512 + t;                                                  \
      int row = s2 >> 2, g = s2 & 3;                                         \
      int sg = (g ^ ((row >> 1) & 3)) << 4;                                  \
      gld16((const char*)Bb + (size_t)(n0 + row) * 512 + kb + sg,            \
            (lb) + 8192 + (size_t)s2 * 16);                                  \
    }                                                                        \
  }

#define COMPJ(lb) {                                                          \
    const char* Al = (lb);                                                   \
    const char* Bl = (lb) + 8192;                                            \
    uint4 af[4], bf[4];                                                      \
    _Pragma("unroll")                                                        \
    for (int mf = 0; mf < 4; ++mf)                                           \
      af[mf] = *(const uint4*)(Al + (wr * 64 + mf * 16 + l16) * 64 + rg);    \
    _Pragma("unroll")                                                        \
    for (int nf = 0; nf < 4; ++nf)                                           \
      bf[nf] = *(const uint4*)(Bl + (wc * 64 + nf * 16 + l16) * 64 + rg);    \
    _Pragma("unroll")                                                        \
    for (int kk = 0; kk < 2; ++kk) {                                         \
      _Pragma("unroll")                                                      \
      for (int mf = 0; mf < 4; ++mf) {                                       \
        long long a8 = ((long long)(kk ? af[mf].w : af[mf].y) << 32) |       \
                       (unsigned int)(kk ? af[mf].z : af[mf].x);             \
        _Pragma("unroll")                                                    \
        for (int nf = 0; nf < 4; ++nf) {                                     \
          long long b8 = ((long long)(kk ? bf[nf].w : bf[nf].y) << 32) |     \
                         (unsigned int)(kk ? bf[nf].z : bf[nf].x);           \
          acc[mf][nf] = __builtin_amdgcn_mfma_f32_16x16x32_fp8_fp8(          \
              a8, b8, acc[mf][nf], 0, 0, 0);                                 \
        }                                                                    \
      }                                                                      \
    }                                                                        \
  }

  char* buf0 = smem;
  char* buf1 = smem + 24576;

  STGJ(0, buf0);
#pragma unroll
  for (int s = 0; s < 8; ++s) {
    char* cb = (s & 1) ? buf1 : buf0;
    char* nb = (s & 1) ? buf0 : buf1;
    if (s < 7) {
      STGJ(s + 1, nb);
      asm volatile("s_waitcnt vmcnt(3)" ::: "memory");
    } else {
      asm volatile("s_waitcnt vmcnt(0)" ::: "memory");
    }
    __builtin_amdgcn_s_barrier();
    __builtin_amdgcn_sched_barrier(0);
    COMPJ(cb);
    __builtin_amdgcn_sched_barrier(0);
    __builtin_amdgcn_s_barrier();
  }
#undef STGJ
#undef COMPJ

  if constexpr (EPI == EPI_Q) {
    float bc[4];
#pragma unroll
    for (int nf = 0; nf < 4; ++nf) bc[nf] = aux[n0 + wc * 64 + nf * 16 + l16];
#pragma unroll
    for (int mf = 0; mf < 4; ++mf) {
#pragma unroll
      for (int r = 0; r < 4; ++r) {
        int row = wr * 64 + mf * 16 + lg * 4 + r;
        int gx = ((row >> 2) & 3) << 4;
#pragma unroll
        for (int nf = 0; nf < 4; ++nf) {
          int cl = wc * 64 + nf * 16 + l16;
          smem[row * 256 + (cl ^ gx)] = (char)f2fp8(acc[mf][nf][r] + bc[nf]);
        }
      }
    }
    __syncthreads();
#pragma unroll
    for (int it = 0; it < 4; ++it) {
      int idx = it * 512 + t;
      int row = idx >> 4, seg = idx & 15;
      int gx = ((row >> 2) & 3) << 4;
      uint4 v = *(const uint4*)(smem + row * 256 + ((seg * 16) ^ gx));
      *(uint4*)(ob + (size_t)(m0 + row) * ldo + n0 + seg * 16) = v;
    }
  } else {  // EPI_V: kmap-packed u32 per 64-key group
#pragma unroll
    for (int mf = 0; mf < 4; ++mf) {
#pragma unroll
      for (int r = 0; r < 4; ++r) {
        int row = wr * 64 + mf * 16 + lg * 4 + r;
        float brow = aux[m0 + row];
        uint32_t pk = 0;
#pragma unroll
        for (int nf = 0; nf < 4; ++nf)
          pk |= (uint32_t)f2fp8(acc[mf][nf][r] + brow) << (8 * nf);
        int blk = (wc ^ lg) << 6;
        *(uint32_t*)(smem + row * 256 + blk + l16 * 4) = pk;
      }
    }
    __syncthreads();
#pragma unroll
    for (int it = 0; it < 4; ++it) {
      int idx = it * 512 + t;
      int row = idx >> 4, seg = idx & 15;
      int blk = ((seg >> 2) ^ ((row >> 2) & 3)) << 6;
      uint4 v = *(const uint4*)(smem + row * 256 + blk + (seg & 3) * 16);
      *(uint4*)(ob + (size_t)(m0 + row) * ldo + n0 + seg * 16) = v;
    }
  }
}

// ============== exp8: 128x256 tile, fp8, BK=64, dbuf + vmcnt(3) =============
// (byte-identical to r12/r13)
__global__ __launch_bounds__(512, 3) void exp8(
    const u8* __restrict__ qk8, float* __restrict__ dsumAll, u8* __restrict__ Pall)
{
  int fid = blockIdx.x;
  int rid = (fid & 7) * 256 + (fid >> 3);
  int z = rid >> 9;
  int r9 = rid & 511;
  int c2 = r9 >> 8;
  int r8 = r9 & 255;
  int sm = r8 >> 6, w6s = r8 & 63;
  int m0 = (c2 * 16 + (sm >> 1) * 8 + (w6s >> 3)) * 128;
  int n0 = ((sm & 1) * 8 + (w6s & 7)) * 256;

  const u8* Ab = qk8 + (size_t)z * ((size_t)N_ * 1024);
  const u8* Bb = Ab + 512;
  float* dsum = dsumAll + (size_t)z * N_;
  u8* Pp = Pall + (size_t)z * (size_t)N_ * N_;

  int t = threadIdx.x, w = t >> 6, l = t & 63;
  int wr = w >> 2, wc = w & 3;
  int l16 = l & 15, lg = l >> 4;

  __shared__ char smem[49152];

  f32x4 acc[4][4] = {};
  int rg = ((lg ^ ((l16 >> 1) & 3)) & 3) << 4;

#define STG8(step, lb) {                                                     \
    size_t kb = (size_t)(step) * 64;                                         \
    {                                                                        \
      int row = t >> 2, g = t & 3;                                           \
      int sg = (g ^ ((row >> 1) & 3)) << 4;                                  \
      gld16((const char*)Ab + (size_t)(m0 + row) * 1024 + kb + sg,           \
            (lb) + (size_t)t * 16);                                          \
    }                                                                        \
    _Pragma("unroll")                                                        \
    for (int i = 0; i < 2; ++i) {                                            \
      int s2 = i * 512 + t;                                                  \
      int row = s2 >> 2, g = s2 & 3;                                         \
      int sg = (g ^ ((row >> 1) & 3)) << 4;                                  \
      gld16((const char*)Bb + (size_t)(n0 + row) * 1024 + kb + sg,           \
            (lb) + 8192 + (size_t)s2 * 16);                                  \
    }                                                                        \
  }

#define COMP8(lb) {                                                          \
    const char* Al = (lb);                                                   \
    const char* Bl = (lb) + 8192;                                            \
    uint4 af[4], bf[4];                                                      \
    _Pragma("unroll")                                                        \
    for (int mf = 0; mf < 4; ++mf)                                           \
      af[mf] = *(const uint4*)(Al + (wr * 64 + mf * 16 + l16) * 64 + rg);    \
    _Pragma("unroll")                                                        \
    for (int nf = 0; nf < 4; ++nf)                                           \
      bf[nf] = *(const uint4*)(Bl + (wc * 64 + nf * 16 + l16) * 64 + rg);    \
    _Pragma("unroll")                                                        \
    for (int kk = 0; kk < 2; ++kk) {                                         \
      _Pragma("unroll")                                                      \
      for (int mf = 0; mf < 4; ++mf) {                                       \
        long long a8 = ((long long)(kk ? af[mf].w : af[mf].y) << 32) |       \
                       (unsigned int)(kk ? af[mf].z : af[mf].x);             \
        _Pragma("unroll")                                                    \
        for (int nf = 0; nf < 4; ++nf) {                                     \
          long long b8 = ((long long)(kk ? bf[nf].w : bf[nf].y) << 32) |     \
                         (unsigned int)(kk ? bf[nf].z : bf[nf].x);           \
          acc[mf][nf] = __builtin_amdgcn_mfma_f32_16x16x32_fp8_fp8(          \
              a8, b8, acc[mf][nf], 0, 0, 0);                                 \
        }                                                                    \
      }                                                                      \
    }                                                                        \
  }

  char* buf0 = smem;
  char* buf1 = smem + 24576;

  STG8(0, buf0);
#pragma unroll
  for (int s = 0; s < 8; ++s) {
    char* cb = (s & 1) ? buf1 : buf0;
    char* nb = (s & 1) ? buf0 : buf1;
    if (s < 7) {
      STG8(s + 1, nb);
      asm volatile("s_waitcnt vmcnt(3)" ::: "memory");
    } else {
      asm volatile("s_waitcnt vmcnt(0)" ::: "memory");
    }
    __builtin_amdgcn_s_barrier();
    __builtin_amdgcn_sched_barrier(0);
    COMP8(cb);
    __builtin_amdgcn_sched_barrier(0);
    __builtin_amdgcn_s_barrier();
  }
#undef STG8
#undef COMP8

#pragma unroll
  for (int mf = 0; mf < 4; ++mf) {
#pragma unroll
    for (int r = 0; r < 4; ++r) {
      int row = wr * 64 + mf * 16 + lg * 4 + r;
      float rs = 0.f;
      uint32_t pk = 0;
#pragma unroll
      for (int nf = 0; nf < 4; ++nf) {
        float p = __builtin_amdgcn_exp2f(acc[mf][nf][r] * SCEXP);
        rs += p;
        pk |= (uint32_t)f2bf8pos(p) << (8 * nf);
      }
      int blk = (wc ^ lg) << 6;
      *(uint32_t*)(smem + row * 256 + blk + l16 * 4) = pk;
      rs += __shfl_xor(rs, 1); rs += __shfl_xor(rs, 2);
      rs += __shfl_xor(rs, 4); rs += __shfl_xor(rs, 8);
      if (l16 == 0) atomicAdd(&dsum[m0 + row], rs);
    }
  }
  __syncthreads();
#pragma unroll
  for (int it = 0; it < 4; ++it) {
    int idx = it * 512 + t;
    int row = idx >> 4, seg = idx & 15;
    int blk = ((seg >> 2) ^ ((row >> 2) & 3)) << 6;
    *(uint4*)(Pp + ((size_t)(m0 + row) * N_ + n0 + seg * 16)) =
        *(const uint4*)(smem + row * 256 + blk + (seg & 3) * 16);
  }
}

// ============== pv8: out = x + vM8 P8^T / denom (e4m3 x e5m2) ===============
// (byte-identical to r12/r13)
__global__ __launch_bounds__(256, 4) void pv8(
    const u8* __restrict__ vM8, const u8* __restrict__ P8,
    const float* __restrict__ denom, const float* __restrict__ x,
    float* __restrict__ out)
{
  int fid = blockIdx.x;
  int rid = (fid & 7) * 64 + (fid >> 3);
  int z = rid >> 7;
  int r7 = rid & 127;
  int n0 = (r7 >> 2) * 128;
  int m0 = (r7 & 3) * 128;

  const u8* Ab = vM8 + (size_t)z * ((size_t)C_ * N_);
  const u8* Bb = P8 + (size_t)z * ((size_t)N_ * N_);
  const float* db = denom + (size_t)z * N_;
  const float* xb = x + (size_t)z * ((size_t)C_ * N_);
  float* ob = out + (size_t)z * ((size_t)C_ * N_);

  int t = threadIdx.x, w = t >> 6, l = t & 63;
  int wr = w >> 1, wc = w & 1;
  int l16 = l & 15, lg = l >> 4;

  __shared__ char smem[32768];

  f32x4 acc[4][4] = {};
  int rg = ((lg ^ ((l16 >> 1) & 3)) & 3) << 4;

#define STGP(step, lb) {                                                     \
    size_t kb = (size_t)(step) * 64;                                         \
    _Pragma("unroll")                                                        \
    for (int i = 0; i < 2; ++i) {                                            \
      int s2 = i * 256 + t;                                                  \
      int row = s2 >> 2, g = s2 & 3;                                         \
      int sg = (g ^ ((row >> 1) & 3)) << 4;                                  \
      gld16((const char*)Ab + (size_t)(m0 + row) * N_ + kb + sg,             \
            (lb) + (size_t)s2 * 16);                                         \
      gld16((const char*)Bb + (size_t)(n0 + row) * N_ + kb + sg,             \
            (lb) + 8192 + (size_t)s2 * 16);                                  \
    }                                                                        \
  }

#define COMPP(lb) {                                                          \
    const char* Al = (lb);                                                   \
    const char* Bl = (lb) + 8192;                                            \
    uint4 af[4], bf[4];                                                      \
    _Pragma("unroll")                                                        \
    for (int mf = 0; mf < 4; ++mf)                                           \
      af[mf] = *(const uint4*)(Al + (wr * 64 + mf * 16 + l16) * 64 + rg);    \
    _Pragma("unroll")                                                        \
    for (int nf = 0; nf < 4; ++nf)                                           \
      bf[nf] = *(const uint4*)(Bl + (wc * 64 + nf * 16 + l16) * 64 + rg);    \
    _Pragma("unroll")                                                        \
    for (int kk = 0; kk < 2; ++kk) {                                         \
      _Pragma("unroll")                                                      \
      for (int mf = 0; mf < 4; ++mf) {                                       \
        long long a8 = ((long long)(kk ? af[mf].w : af[mf].y) << 32) |       \
                       (unsigned int)(kk ? af[mf].z : af[mf].x);             \
        _Pragma("unroll")                                                    \
        for (int nf = 0; nf < 4; ++nf) {                                     \
          long long b8 = ((long long)(kk ? bf[nf].w : bf[nf].y) << 32) |     \
                         (unsigned int)(kk ? bf[nf].z : bf[nf].x);           \
          acc[mf][nf] = __builtin_amdgcn_mfma_f32_16x16x32_fp8_bf8(          \
              a8, b8, acc[mf][nf], 0, 0, 0);                                 \
        }                                                                    \
      }                                                                      \
    }                                                                        \
  }

  char* buf0 = smem;
  char* buf1 = smem + 16384;

  STGP(0, buf0);
#pragma unroll 2
  for (int s = 0; s < 64; ++s) {
    char* cb = (s & 1) ? buf1 : buf0;
    char* nb = (s & 1) ? buf0 : buf1;
    if (s < 63) {
      STGP(s + 1, nb);
      asm volatile("s_waitcnt vmcnt(4)" ::: "memory");
    } else {
      asm volatile("s_waitcnt vmcnt(0)" ::: "memory");
    }
    __builtin_amdgcn_s_barrier();
    __builtin_amdgcn_sched_barrier(0);
    COMPP(cb);
    __builtin_amdgcn_sched_barrier(0);
    __builtin_amdgcn_s_barrier();
  }
#undef STGP
#undef COMPP

  float rd[4];
#pragma unroll
  for (int nf = 0; nf < 4; ++nf)
    rd[nf] = 1.0f / db[n0 + wc * 64 + nf * 16 + l16];
#pragma unroll
  for (int mf = 0; mf < 4; ++mf) {
#pragma unroll
    for (int r = 0; r < 4; ++r) {
      int row = m0 + wr * 64 + mf * 16 + lg * 4 + r;
#pragma unroll
      for (int nf = 0; nf < 4; ++nf) {
        int col = n0 + wc * 64 + nf * 16 + l16;
        size_t o = (size_t)row * N_ + col;
        ob[o] = xb[o] + acc[mf][nf][r] * rd[nf];
      }
    }
  }
}

// ================== round-1 fallback path (tiny ws) =========================
__global__ __launch_bounds__(256) void gemm_abT(
    const u16* __restrict__ A, const u16* __restrict__ Bm,
    const float* __restrict__ bias, u16* __restrict__ out,
    int ldo, int bias_is_row)
{
  int w = threadIdx.x >> 6, l = threadIdx.x & 63;
  int l16 = l & 15, lg = l >> 4;
  int m0 = blockIdx.x * 128 + (w >> 1) * 64;
  int n0 = blockIdx.y * 128 + (w & 1) * 64;
  f32x4 acc[4][4] = {};
  const u16* Ab = A  + (size_t)(m0 + l16) * 512 + lg * 8;
  const u16* Bb = Bm + (size_t)(n0 + l16) * 512 + lg * 8;
  for (int kc = 0; kc < 512; kc += 32) {
    bf16x8 af[4], bf[4];
#pragma unroll
    for (int i = 0; i < 4; ++i) af[i] = ld16g(Ab + (size_t)(i * 16) * 512 + kc);
#pragma unroll
    for (int j = 0; j < 4; ++j) bf[j] = ld16g(Bb + (size_t)(j * 16) * 512 + kc);
#pragma unroll
    for (int i = 0; i < 4; ++i)
#pragma unroll
      for (int j = 0; j < 4; ++j)
        acc[i][j] = __builtin_amdgcn_mfma_f32_16x16x32_bf16(af[i], bf[j], acc[i][j], 0, 0, 0);
  }
#pragma unroll
  for (int i = 0; i < 4; ++i) {
#pragma unroll
    for (int j = 0; j < 4; ++j) {
      int col = n0 + j * 16 + l16;
#pragma unroll
      for (int r = 0; r < 4; ++r) {
        int row = m0 + i * 16 + lg * 4 + r;
        float v = acc[i][j][r] + (bias_is_row ? bias[row] : bias[col]);
        out[(size_t)row * ldo + col] = f2bf(v);
      }
    }
  }
}

#define NQ 32
#define NKB 64
__global__ __launch_bounds__(512) void attn_kernel(
    const u16* __restrict__ qT, const u16* __restrict__ kT, const u16* __restrict__ vM,
    const float* __restrict__ x, float* __restrict__ out)
{
  int b = blockIdx.y;
  int nq0 = blockIdx.x * NQ;
  const u16* qTb = qT + (size_t)b * N_ * C_;
  const u16* kTb = kT + (size_t)b * N_ * C_;
  const u16* vb  = vM + (size_t)b * C_ * N_;
  const float* xb = x + (size_t)b * C_ * N_;
  float* ob = out + (size_t)b * C_ * N_;

  int tid = threadIdx.x;
  int w = tid >> 6, l = tid & 63, l16 = l & 15, lg = l >> 4;
  int nqf = w & 1, nkf = w >> 1;
  int c0 = w * 64;

  __shared__ u16 qlds[32][520];
  __shared__ u16 Plds[32][72];
  __shared__ float dpart[32][16];
  __shared__ float dfin[32];

  for (int idx = tid; idx < 32 * 64; idx += 512) {
    int row = idx >> 6, cg = idx & 63;
    *(uint4*)&qlds[row][cg * 8] = *(const uint4*)(qTb + (size_t)(nq0 + row) * C_ + cg * 8);
  }
  __syncthreads();

  f32x4 acc[2][4] = {};
  float dreg = 0.f;
  int drow = tid >> 4, dcol = (tid & 15) * 4;

  for (int nk0 = 0; nk0 < N_; nk0 += NKB) {
    f32x4 s = {0.f, 0.f, 0.f, 0.f};
    const u16* krow = kTb + (size_t)(nk0 + nkf * 16 + l16) * C_ + lg * 8;
#pragma unroll 4
    for (int kc = 0; kc < 16; ++kc) {
      U16B tq; tq.u = *(const uint4*)&qlds[nqf * 16 + l16][kc * 32 + lg * 8];
      bf16x8 kf = ld16g(krow + kc * 32);
      s = __builtin_amdgcn_mfma_f32_16x16x32_bf16(tq.v, kf, s, 0, 0, 0);
    }
    __syncthreads();
#pragma unroll
    for (int r = 0; r < 4; ++r) {
      float p = __builtin_amdgcn_exp2f(s[r] * SCEXP);
      Plds[nqf * 16 + lg * 4 + r][nkf * 16 + l16] = f2bf(p);
    }
    __syncthreads();
#pragma unroll
    for (int r = 0; r < 4; ++r) dreg += bf2f(Plds[drow][dcol + r]);
#pragma unroll
    for (int kk = 0; kk < 2; ++kk) {
      bf16x8 pf[2];
#pragma unroll
      for (int i = 0; i < 2; ++i) {
        U16B t2; t2.u = *(const uint4*)&Plds[i * 16 + l16][kk * 32 + lg * 8];
        pf[i] = t2.v;
      }
#pragma unroll
      for (int j = 0; j < 4; ++j) {
        bf16x8 vf = ld16g(vb + (size_t)(c0 + j * 16 + l16) * N_ + nk0 + kk * 32 + lg * 8);
#pragma unroll
        for (int i = 0; i < 2; ++i)
          acc[i][j] = __builtin_amdgcn_mfma_f32_16x16x32_bf16(pf[i], vf, acc[i][j], 0, 0, 0);
      }
    }
  }

  dpart[drow][tid & 15] = dreg;
  __syncthreads();
  if (tid < 32) {
    float s2 = 0.f;
#pragma unroll
    for (int g = 0; g < 16; ++g) s2 += dpart[tid][g];
    dfin[tid] = s2;
  }
  __syncthreads();

#pragma unroll
  for (int i = 0; i < 2; ++i) {
    float dinv[4];
#pragma unroll
    for (int r = 0; r < 4; ++r) dinv[r] = 1.f / dfin[i * 16 + lg * 4 + r];
    int nbase = nq0 + i * 16 + lg * 4;
#pragma unroll
    for (int j = 0; j < 4; ++j) {
      int c = c0 + j * 16 + l16;
      float4 xv = *(const float4*)(xb + (size_t)c * N_ + nbase);
      float4 o;
      o.x = xv.x + acc[i][j][0] * dinv[0];
      o.y = xv.y + acc[i][j][1] * dinv[1];
      o.z = xv.z + acc[i][j][2] * dinv[2];
      o.w = xv.w + acc[i][j][3] * dinv[3];
      *(float4*)(ob + (size_t)c * N_ + nbase) = o;
    }
  }
}

extern "C" void kernel_launch(void* const* d_in, const int* in_sizes, int n_in,
                              void* d_out, int out_size, void* d_ws, size_t ws_size,
                              hipStream_t stream) {
  (void)in_sizes; (void)n_in; (void)out_size;
  const float* x  = (const float*)d_in[0];
  const float* wq = (const float*)d_in[1];
  const float* bq = (const float*)d_in[2];
  const float* wk = (const float*)d_in[3];
  const float* bk = (const float*)d_in[4];
  const float* wv = (const float*)d_in[5];
  const float* bv = (const float*)d_in[6];
  float* out = (float*)d_out;
  char* ws = (char*)d_ws;

  const size_t NC = (size_t)N_ * C_;        // 2097152 elems
  const size_t NEED = 101535744;

  if (ws_size >= NEED) {
    u8*    wqk8  = (u8*)(ws);               // 512 KB: wq8 | wk8
    u8*    wv8   = (u8*)(ws + 524288);      // 256 KB
    float* bqk   = (float*)(ws + 786432);   // 4 KB
    float* mu    = (float*)(ws + 790528);   // 8 KB
    float* rstd  = (float*)(ws + 798720);   // 8 KB
    u8*    h8    = (u8*)(ws + 806912);      //  8.4 MB (B,N,C) fp8 natural
    u8*    qk8   = (u8*)(ws + 9195520);     // 16.8 MB (B,N,1024) fp8, C-perm
    u8*    vM8   = (u8*)(ws + 25972736);    //  8.4 MB (B,C,N) fp8 key-kmap
    float* denom = (float*)(ws + 34361344); // 64 KB
    u8*    P8    = (u8*)(ws + 34426880);    // 67.1 MB (B,N,N) bf8 key-kmap

    prep_wb<<<769, 256, 0, stream>>>(wq, wk, wv, bq, bk, wqk8, wv8, bqk);
    inorm_stats<<<B_ * C_, 256, 0, stream>>>(x, mu, rstd);
    norm_h8<<<dim3(N_ / 64, C_ / 128, B_), 256, 0, stream>>>(x, mu, rstd, h8);
    hipMemsetAsync(denom, 0, 4 * N_ * sizeof(float), stream);

    // q+k projection (fp8): qk8[n][o] = sum_c h8[n][c] wqk8[o][c] + bqk[o]
    proj8<EPI_Q><<<dim3(32, 4, 4), 512, 0, stream>>>(
        h8, wqk8, bqk, qk8, (long)NC, 0, (long)N_ * 1024, 1024);
    // v projection (fp8): vM8[c][n] = sum_ch wv8[c][ch] h8[n][ch] + bv[c]
    proj8<EPI_V><<<dim3(4, 16, 4), 512, 0, stream>>>(
        wv8, h8, bv, vM8, 0, (long)NC, (long)NC, 4096);

    // P8 = bf8(exp(scale * q k^T)), unrounded rowsums -> denom
    exp8<<<2048, 512, 0, stream>>>(qk8, denom, P8);

    // out = x + vM8 P8^T / denom
    pv8<<<512, 256, 0, stream>>>(vM8, P8, denom, x, out);
  } else {
    // ---- fallback: round-1 path (65.5 MB ws) ----
    u16*   wbf_q = (u16*)(ws);
    u16*   wbf_k = (u16*)(ws + 524288);
    u16*   wbf_v = (u16*)(ws + 1048576);
    float* mu    = (float*)(ws + 1572864);
    float* rstd  = (float*)(ws + 1581056);
    u16*   hT    = (u16*)(ws + 1589248);
    u16*   qT    = (u16*)(ws + 18366464);
    u16*   kT    = (u16*)(ws + 35143680);
    u16*   vM    = (u16*)(ws + 51920896);

    cvt_w<<<256, 256, 0, stream>>>(wq, wbf_q);
    cvt_w<<<256, 256, 0, stream>>>(wk, wbf_k);
    cvt_w<<<256, 256, 0, stream>>>(wv, wbf_v);
    inorm_stats<<<B_ * C_, 256, 0, stream>>>(x, mu, rstd);
    norm_transpose<<<dim3(N_ / 64, C_ / 64, B_), 256, 0, stream>>>(x, mu, rstd, hT);

    for (int b = 0; b < B_; ++b) {
      const u16* hTb = hT + (size_t)b * NC;
      u16* qTb = qT + (size_t)b * NC;
      u16* kTb = kT + (size_t)b * NC;
      u16* vMb = vM + (size_t)b * NC;
      gemm_abT<<<dim3(N_ / 128, C_ / 128), 256, 0, stream>>>(hTb, wbf_q, bq, qTb, C_, 0);
      gemm_abT<<<dim3(N_ / 128, C_ / 128), 256, 0, stream>>>(hTb, wbf_k, bk, kTb, C_, 0);
      gemm_abT<<<dim3(C_ / 128, N_ / 128), 256, 0, stream>>>(wbf_v, hTb, bv, vMb, N_, 1);
    }
    attn_kernel<<<dim3(N_ / NQ, B_), 512, 0, stream>>>(qT, kT, vM, x, out);
  }
}